// Round 20
// baseline (346.028 us; speedup 1.0000x reference)
//
#include <hip/hip_runtime.h>
#include <hip/hip_bf16.h>
#include <cstddef>

#define B_ 4
#define T_ 2048
#define D_ 1024
#define H_ 16
#define HS_ 64
#define QKS_ 2048   // fused QK row stride

typedef short short8 __attribute__((ext_vector_type(8)));
typedef float f32x4 __attribute__((ext_vector_type(4)));

__device__ __forceinline__ unsigned short f2b(float x) {
    __hip_bfloat16 b = __float2bfloat16(x);
    return *reinterpret_cast<unsigned short*>(&b);
}

__device__ __forceinline__ void gload_lds16(const void* g, void* l) {
    __builtin_amdgcn_global_load_lds((const __attribute__((address_space(1))) void*)g,
                                     (__attribute__((address_space(3))) void*)l, 16, 0, 0);
}

// ---------------- LayerNorm: fp32 in -> bf16 out ----------------
__global__ __launch_bounds__(256) void ln_kernel(const float* __restrict__ X,
                                                 const float* __restrict__ g,
                                                 const float* __restrict__ be,
                                                 unsigned short* __restrict__ O)
{
    const int row = blockIdx.x;
    const int tid = threadIdx.x;
    const float* xr = X + (size_t)row * D_;
    float4 xv = *reinterpret_cast<const float4*>(xr + tid * 4);
    float s  = xv.x + xv.y + xv.z + xv.w;
    float s2 = xv.x * xv.x + xv.y * xv.y + xv.z * xv.z + xv.w * xv.w;
#pragma unroll
    for (int off = 32; off > 0; off >>= 1) {
        s  += __shfl_xor(s,  off);
        s2 += __shfl_xor(s2, off);
    }
    __shared__ float red[8];
    const int wid = tid >> 6, lane = tid & 63;
    if (lane == 0) { red[wid * 2] = s; red[wid * 2 + 1] = s2; }
    __syncthreads();
    s  = red[0] + red[2] + red[4] + red[6];
    s2 = red[1] + red[3] + red[5] + red[7];
    const float mu  = s * (1.0f / D_);
    const float var = s2 * (1.0f / D_) - mu * mu;
    const float r   = rsqrtf(var + 1e-5f);
    float4 gv = *reinterpret_cast<const float4*>(g  + tid * 4);
    float4 bv = *reinterpret_cast<const float4*>(be + tid * 4);
    ushort4 ov;
    ov.x = f2b((xv.x - mu) * r * gv.x + bv.x);
    ov.y = f2b((xv.y - mu) * r * gv.y + bv.y);
    ov.z = f2b((xv.z - mu) * r * gv.z + bv.z);
    ov.w = f2b((xv.w - mu) * r * gv.w + bv.w);
    *reinterpret_cast<ushort4*>(O + (size_t)row * D_ + tid * 4) = ov;
}

// ---------------- all weight transposes fused into one kernel ----------------
__global__ __launch_bounds__(256) void transpose_all(const float* __restrict__ Wq,
                                                     const float* __restrict__ Wk,
                                                     const float* __restrict__ Wv,
                                                     const float* __restrict__ Wo,
                                                     const float* __restrict__ W1,
                                                     const float* __restrict__ W2,
                                                     unsigned short* __restrict__ Wtqkv,
                                                     unsigned short* __restrict__ Wto,
                                                     unsigned short* __restrict__ Wt1,
                                                     unsigned short* __restrict__ Wt2)
{
    __shared__ float tile[32][33];
    const int tx = threadIdx.x & 31, ty = threadIdx.x >> 5;
    int s = blockIdx.x;

    if (s < 3072) {   // headed: out[noff+n][k] = in[n>>6][k][n&63]
        const float* in = (s < 1024) ? Wq : (s < 2048) ? Wk : Wv;
        const int noff = (s < 1024) ? 0 : (s < 2048) ? D_ : 2 * D_;
        s &= 1023;
        const int bn = (s & 31) * 32, bk = (s >> 5) * 32;
        const int head = bn >> 6, s0 = bn & 63;
#pragma unroll
        for (int i = 0; i < 32; i += 8)
            tile[ty + i][tx] = in[(size_t)head * D_ * HS_ + (size_t)(bk + ty + i) * HS_ + s0 + tx];
        __syncthreads();
#pragma unroll
        for (int i = 0; i < 32; i += 8)
            Wtqkv[(size_t)(noff + bn + ty + i) * D_ + bk + tx] = f2b(tile[tx][ty + i]);
        return;
    }
    s -= 3072;
    const float* in; unsigned short* out; int K, N, bn, bk;
    if (s < 1024)      { in = Wo; out = Wto; K = D_;     N = D_;     bn = (s & 31) * 32;  bk = (s >> 5) * 32; }
    else if (s < 5120) { s -= 1024; in = W1; out = Wt1; K = D_;     N = 4 * D_; bn = (s & 127) * 32; bk = (s >> 7) * 32; }
    else               { s -= 5120; in = W2; out = Wt2; K = 4 * D_; N = D_;     bn = (s & 31) * 32;  bk = (s >> 5) * 32; }
#pragma unroll
    for (int i = 0; i < 32; i += 8)
        tile[ty + i][tx] = in[(size_t)(bk + ty + i) * N + bn + tx];
    __syncthreads();
#pragma unroll
    for (int i = 0; i < 32; i += 8)
        out[(size_t)(bn + ty + i) * K + bk + tx] = f2b(tile[tx][ty + i]);
}

// ---------------- 256x256 bf16 MFMA GEMM, 4-phase interleaved staging ----------------
// OUT_BF16 epilogue goes through LDS for full-cache-line coalesced stores.
template<bool BIAS, bool RELU, bool RESID, bool OUT_BF16, bool SCALEQ>
__global__ __launch_bounds__(512, 1) void gemm_sq(const unsigned short* __restrict__ A,
                                                  const unsigned short* __restrict__ Bt,
                                                  const float* __restrict__ bias,
                                                  const float* __restrict__ resid,
                                                  float* __restrict__ Cf,
                                                  unsigned short* __restrict__ Cb,
                                                  int M, int N, int K)
{
    constexpr int BUFS = 16384 + 16384;   // shorts: A 256x64 + B 256x64
    __shared__ __attribute__((aligned(128))) unsigned short lds[2 * BUFS];

    const int tid = threadIdx.x, l = tid & 63, w = tid >> 6;
    const int wRow = w >> 2, wCol = w & 3;
    const int lr = l & 15, lq = l >> 4;

    const int gx = gridDim.x;
    const int nwg = gx * (int)gridDim.y;
    const int orig = (int)blockIdx.y * gx + (int)blockIdx.x;
    const int xcd = orig & 7, lo = orig >> 3;
    const int q8 = nwg >> 3, r8 = nwg & 7;
    const int wg = (xcd < r8 ? xcd * (q8 + 1) : r8 * (q8 + 1) + (xcd - r8) * q8) + lo;
    const int bm = wg / gx, bn = wg % gx;

    const int nt = K >> 6;

    auto ISSUE_HALF = [&](int t, int half) {
        const size_t kof = (size_t)t * 64;
        const int buf = t & 1;
        const unsigned short* src = (half < 2) ? A : Bt;
        const int rb = ((half < 2) ? bm : bn) * 256 + (half & 1) * 128;
        const int lb = buf * BUFS + ((half >= 2) ? 16384 : 0) + (half & 1) * 128 * 64;
#pragma unroll
        for (int p = 0; p < 2; ++p) {
            const int j = p * 512 + tid;
            const int row = j >> 3, ci = j & 7;
            gload_lds16(src + (size_t)(rb + row) * K + kof + ((ci ^ (row & 7)) * 8),
                        &lds[lb + j * 8]);
        }
    };

    f32x4 acc[8][4];
#pragma unroll
    for (int i = 0; i < 8; ++i)
#pragma unroll
        for (int j = 0; j < 4; ++j) acc[i][j] = (f32x4){0.f, 0.f, 0.f, 0.f};

    short8 af[4][2], bf[4][2];
    const int swz = lr & 7;

#pragma unroll
    for (int h = 0; h < 4; ++h) ISSUE_HALF(0, h);

    for (int t = 0; t < nt; ++t) {
        const unsigned short* As = &lds[(t & 1) * BUFS];
        const unsigned short* Bs = As + 16384;
        const bool more = (t + 1 < nt);

        asm volatile("s_waitcnt vmcnt(0)" ::: "memory");
        __builtin_amdgcn_s_barrier();

        if (more) ISSUE_HALF(t + 1, 0);
#pragma unroll
        for (int mi = 0; mi < 4; ++mi) {
            const int row = wRow * 128 + mi * 16 + lr;
#pragma unroll
            for (int ks = 0; ks < 2; ++ks)
                af[mi][ks] = *reinterpret_cast<const short8*>(&As[row * 64 + (((ks * 4 + lq) ^ swz) * 8)]);
        }
#pragma unroll
        for (int nj = 0; nj < 2; ++nj) {
            const int rowB = wCol * 64 + nj * 16 + lr;
#pragma unroll
            for (int ks = 0; ks < 2; ++ks)
                bf[nj][ks] = *reinterpret_cast<const short8*>(&Bs[rowB * 64 + (((ks * 4 + lq) ^ swz) * 8)]);
        }
        asm volatile("s_waitcnt lgkmcnt(0)" ::: "memory");
        __builtin_amdgcn_sched_barrier(0);
        __builtin_amdgcn_s_setprio(1);
#pragma unroll
        for (int mi = 0; mi < 4; ++mi)
#pragma unroll
            for (int nj = 0; nj < 2; ++nj)
#pragma unroll
                for (int ks = 0; ks < 2; ++ks)
                    acc[mi][nj] = __builtin_amdgcn_mfma_f32_16x16x32_bf16(af[mi][ks], bf[nj][ks], acc[mi][nj], 0, 0, 0);
        __builtin_amdgcn_s_setprio(0);

        if (more) ISSUE_HALF(t + 1, 1);
#pragma unroll
        for (int nj = 2; nj < 4; ++nj) {
            const int rowB = wCol * 64 + nj * 16 + lr;
#pragma unroll
            for (int ks = 0; ks < 2; ++ks)
                bf[nj][ks] = *reinterpret_cast<const short8*>(&Bs[rowB * 64 + (((ks * 4 + lq) ^ swz) * 8)]);
        }
        asm volatile("s_waitcnt lgkmcnt(0)" ::: "memory");
        __builtin_amdgcn_sched_barrier(0);
        __builtin_amdgcn_s_setprio(1);
#pragma unroll
        for (int mi = 0; mi < 4; ++mi)
#pragma unroll
            for (int nj = 2; nj < 4; ++nj)
#pragma unroll
                for (int ks = 0; ks < 2; ++ks)
                    acc[mi][nj] = __builtin_amdgcn_mfma_f32_16x16x32_bf16(af[mi][ks], bf[nj][ks], acc[mi][nj], 0, 0, 0);
        __builtin_amdgcn_s_setprio(0);

        if (more) { ISSUE_HALF(t + 1, 2); ISSUE_HALF(t + 1, 3); }
#pragma unroll
        for (int mi = 0; mi < 4; ++mi) {
            const int row = wRow * 128 + (4 + mi) * 16 + lr;
#pragma unroll
            for (int ks = 0; ks < 2; ++ks)
                af[mi][ks] = *reinterpret_cast<const short8*>(&As[row * 64 + (((ks * 4 + lq) ^ swz) * 8)]);
        }
        asm volatile("s_waitcnt lgkmcnt(0)" ::: "memory");
        __builtin_amdgcn_sched_barrier(0);
        __builtin_amdgcn_s_setprio(1);
#pragma unroll
        for (int mi = 0; mi < 4; ++mi)
#pragma unroll
            for (int nj = 0; nj < 2; ++nj)
#pragma unroll
                for (int ks = 0; ks < 2; ++ks)
                    acc[4 + mi][nj] = __builtin_amdgcn_mfma_f32_16x16x32_bf16(af[mi][ks], bf[nj][ks], acc[4 + mi][nj], 0, 0, 0);
        __builtin_amdgcn_s_setprio(0);

        __builtin_amdgcn_s_setprio(1);
#pragma unroll
        for (int mi = 0; mi < 4; ++mi)
#pragma unroll
            for (int nj = 2; nj < 4; ++nj)
#pragma unroll
                for (int ks = 0; ks < 2; ++ks)
                    acc[4 + mi][nj] = __builtin_amdgcn_mfma_f32_16x16x32_bf16(af[mi][ks], bf[nj][ks], acc[4 + mi][nj], 0, 0, 0);
        __builtin_amdgcn_s_setprio(0);
    }

    const int m0 = bm * 256 + wRow * 128;
    const int n0 = bn * 256 + wCol * 64;
    if constexpr (OUT_BF16) {
        // coalesced epilogue: stage wave's 128x64 bf16 subtile in LDS, store 16B/lane
        __syncthreads();                           // all waves done with pipeline LDS
        unsigned short* ldsE = lds + w * 8192;     // [128 rows][64 cols]
#pragma unroll
        for (int nf = 0; nf < 4; ++nf) {
            const int col = n0 + nf * 16 + lr;
            const float bv = BIAS ? bias[col] : 0.0f;
#pragma unroll
            for (int mf = 0; mf < 8; ++mf) {
#pragma unroll
                for (int r = 0; r < 4; ++r) {
                    float c = acc[mf][nf][r] + bv;
                    if (RELU) c = fmaxf(c, 0.0f);
                    if (SCALEQ) { if (col < D_) c *= 0.18033688f; }
                    ldsE[(mf * 16 + lq * 4 + r) * 64 + nf * 16 + lr] = f2b(c);
                }
            }
        }
        asm volatile("s_waitcnt lgkmcnt(0)" ::: "memory");   // own-wave writes visible
        const int lg = l >> 3, lc = (l & 7) * 8;
#pragma unroll
        for (int i = 0; i < 16; ++i) {
            const int rowl = i * 8 + lg;
            short8 v = *reinterpret_cast<const short8*>(&ldsE[rowl * 64 + lc]);
            *reinterpret_cast<short8*>(&Cb[(size_t)(m0 + rowl) * N + n0 + lc]) = v;
        }
    } else {
#pragma unroll
        for (int nf = 0; nf < 4; ++nf) {
            const int col = n0 + nf * 16 + lr;
            const float bv = BIAS ? bias[col] : 0.0f;
#pragma unroll
            for (int mf = 0; mf < 8; ++mf) {
#pragma unroll
                for (int r = 0; r < 4; ++r) {
                    const int row = m0 + mf * 16 + lq * 4 + r;
                    float c = acc[mf][nf][r] + bv;
                    if (RELU) c = fmaxf(c, 0.0f);
                    if (RESID) c += resid[(size_t)row * N + col];
                    if (SCALEQ) { if (col < D_) c *= 0.18033688f; }
                    Cf[(size_t)row * N + col] = c;
                }
            }
        }
    }
}

// ---------------- 128(M)x256(N) bf16 MFMA GEMM, BK=32, 3-buffer, 2 blocks/CU ----------------
// 72 KB LDS -> 2 co-resident blocks (cross-block stall overlap). Counted vmcnt(3).
// LDS content swizzle: chunk ci of row holds global chunk ci^((row>>1)&3) (gemm_p8-proven).
// VONLY: ALL blocks' 128x256 tiles transposed THROUGH LDS (sigma at LDS-write), coalesced to
//   Vt[((b*16+head)*64+s)][(t&~63)+sigma(t&63)], sigma(k)=(k&15)*4+(k>>4).
template<bool BIAS, bool RELU, bool RESID, bool OUT_BF16, bool SCALEQ, bool VONLY>
__global__ __launch_bounds__(512, 2) void gemm_sq2(const unsigned short* __restrict__ A,
                                                   const unsigned short* __restrict__ Bt,
                                                   const float* __restrict__ bias,
                                                   const float* __restrict__ resid,
                                                   float* __restrict__ Cf,
                                                   unsigned short* __restrict__ Cb,
                                                   unsigned short* __restrict__ Vt,
                                                   int M, int N, int K)
{
    constexpr int BUFS = 4096 + 8192;   // shorts: A 128x32 + B 256x32 (24 KB)
    __shared__ __attribute__((aligned(128))) unsigned short lds[3 * BUFS];   // 72 KB

    const int tid = threadIdx.x, l = tid & 63, w = tid >> 6;
    const int wRow = w >> 2, wCol = w & 3;
    const int lr = l & 15, lq = l >> 4;

    const int gx = gridDim.x;
    const int nwg = gx * (int)gridDim.y;
    const int orig = (int)blockIdx.y * gx + (int)blockIdx.x;
    const int xcd = orig & 7, lo = orig >> 3;
    const int q8 = nwg >> 3, r8 = nwg & 7;
    const int wg = (xcd < r8 ? xcd * (q8 + 1) : r8 * (q8 + 1) + (xcd - r8) * q8) + lo;
    const int bm = wg / gx, bn = wg % gx;

    const int nt = K >> 5;

    auto ISSUE = [&](int t, int buf) {
        const size_t kof = (size_t)t * 32;
        {   // A: 128 rows x 4 chunks = 512, 1/thread
            const int row = tid >> 2, ci = tid & 3;
            gload_lds16(A + (size_t)(bm * 128 + row) * K + kof + ((ci ^ ((row >> 1) & 3)) * 8),
                        &lds[buf * BUFS + tid * 8]);
        }
#pragma unroll
        for (int p = 0; p < 2; ++p) {   // B: 256 rows x 4 chunks = 1024, 2/thread
            const int j = p * 512 + tid;
            const int row = j >> 2, ci = j & 3;
            gload_lds16(Bt + (size_t)(bn * 256 + row) * K + kof + ((ci ^ ((row >> 1) & 3)) * 8),
                        &lds[buf * BUFS + 4096 + j * 8]);
        }
    };

    f32x4 acc[4][4];
#pragma unroll
    for (int i = 0; i < 4; ++i)
#pragma unroll
        for (int j = 0; j < 4; ++j) acc[i][j] = (f32x4){0.f, 0.f, 0.f, 0.f};

    short8 af[4], bf[4];

    ISSUE(0, 0);
    if (nt > 1) ISSUE(1, 1);

    for (int t = 0; t < nt; ++t) {
        const unsigned short* As = &lds[(t % 3) * BUFS];
        const unsigned short* Bs = As + 4096;
        if (t + 1 < nt) asm volatile("s_waitcnt vmcnt(3)" ::: "memory");
        else            asm volatile("s_waitcnt vmcnt(0)" ::: "memory");
        __builtin_amdgcn_s_barrier();          // tile t landed; tile t-1 readers done
        if (t + 2 < nt) ISSUE(t + 2, (t + 2) % 3);

#pragma unroll
        for (int mi = 0; mi < 4; ++mi) {
            const int row = wRow * 64 + mi * 16 + lr;
            af[mi] = *reinterpret_cast<const short8*>(&As[row * 32 + ((lq ^ ((row >> 1) & 3)) * 8)]);
        }
#pragma unroll
        for (int nj = 0; nj < 4; ++nj) {
            const int rowB = wCol * 64 + nj * 16 + lr;
            bf[nj] = *reinterpret_cast<const short8*>(&Bs[rowB * 32 + ((lq ^ ((rowB >> 1) & 3)) * 8)]);
        }
        asm volatile("s_waitcnt lgkmcnt(0)" ::: "memory");
        __builtin_amdgcn_sched_barrier(0);
        __builtin_amdgcn_s_setprio(1);
#pragma unroll
        for (int mi = 0; mi < 4; ++mi)
#pragma unroll
            for (int nj = 0; nj < 4; ++nj)
                acc[mi][nj] = __builtin_amdgcn_mfma_f32_16x16x32_bf16(af[mi], bf[nj], acc[mi][nj], 0, 0, 0);
        __builtin_amdgcn_s_setprio(0);
    }

    // ---- epilogue
    if (VONLY) {
        // transpose 128x256 tile through LDS, coalesced store to Vt.
        __syncthreads();                      // all waves done reading pipeline LDS
        unsigned short* ldsT = lds;           // [256 cols][136] shorts = 68 KB <= 72 KB
        const int n0l = wCol * 64;
        const int m0l = wRow * 64;
#pragma unroll
        for (int nf = 0; nf < 4; ++nf) {
            const int cl = n0l + nf * 16 + lr;
#pragma unroll
            for (int mf = 0; mf < 4; ++mf) {
#pragma unroll
                for (int r = 0; r < 4; ++r) {
                    const int rl = m0l + mf * 16 + lq * 4 + r;
                    const int pos = (rl & 64) + (((rl & 15) << 2) | ((rl >> 4) & 3)); // sigma
                    ldsT[cl * 136 + pos] = f2b(acc[mf][nf][r]);
                }
            }
        }
        __syncthreads();
        const int rowT = tid >> 1, half = tid & 1;
        const int colV = bn * 256 + rowT;
        const int hd = colV >> 6, sdim = colV & 63;
        const int bb = bm >> 4;
        const int tt0 = (bm & 15) * 128 + half * 64;
        unsigned short* dst = Vt + (((size_t)(bb * H_ + hd) * 64 + sdim) << 11) + tt0;
        const unsigned short* srcl = &ldsT[rowT * 136 + half * 64];
#pragma unroll
        for (int i = 0; i < 8; ++i)
            *reinterpret_cast<short8*>(dst + i * 8) =
                *reinterpret_cast<const short8*>(srcl + i * 8);
        return;
    }

    const int m0 = bm * 128 + wRow * 64;
    const int n0 = bn * 256 + wCol * 64;
#pragma unroll
    for (int nf = 0; nf < 4; ++nf) {
        const int col = n0 + nf * 16 + lr;
        const float bv = BIAS ? bias[col] : 0.0f;
#pragma unroll
        for (int mf = 0; mf < 4; ++mf) {
#pragma unroll
            for (int r = 0; r < 4; ++r) {
                const int row = m0 + mf * 16 + lq * 4 + r;
                float c = acc[mf][nf][r] + bv;
                if (RELU) c = fmaxf(c, 0.0f);
                if (RESID) c += resid[(size_t)row * N + col];
                if (SCALEQ) { if (col < D_) c *= 0.18033688f; }
                if (OUT_BF16) Cb[(size_t)row * N + col] = f2b(c);
                else          Cf[(size_t)row * N + col] = c;
            }
        }
    }
}

// ---------------- MFMA flash attention: paired Q-tiles, shared K/V sweep ----------------
// UNNORMALIZED exp2 softmax; denom via ones-MFMA row-sum.
// Q/K from fused QK buffer (stride 2048, K at +1024); V pre-transposed+sigma in Vt.
template<bool MASKED>
__device__ __forceinline__ void attn_chunk(
    const unsigned short* __restrict__ ksb,           // Ks[bf] 64x64 (chunk-XOR content)
    const unsigned short* __restrict__ vsb,           // Vs[bf] 64x64 (chunk-XOR content, rows=dims)
    unsigned short (* __restrict__ psw)[72],          // this wave's P [16][72] (j-permuted cols)
    const short8* aq, f32x4* o,
    int lr, int lq, int wl)
{
    const short8 vone = {0x3F80, 0x3F80, 0x3F80, 0x3F80, 0x3F80, 0x3F80, 0x3F80, 0x3F80};
    f32x4 s[4];
#pragma unroll
    for (int kb = 0; kb < 4; ++kb) s[kb] = (f32x4){0.f, 0.f, 0.f, 0.f};
    __builtin_amdgcn_s_setprio(1);
#pragma unroll
    for (int kb = 0; kb < 4; ++kb) {
        if (MASKED && kb > wl) continue;
        const int row = kb * 16 + lr;
        const int sw = row & 7;
#pragma unroll
        for (int ks = 0; ks < 2; ++ks) {
            const int ch = (ks * 4 + lq) ^ sw;
            const short8 bk = *reinterpret_cast<const short8*>(&ksb[row * 64 + ch * 8]);
            s[kb] = __builtin_amdgcn_mfma_f32_16x16x32_bf16(aq[ks], bk, s[kb], 0, 0, 0);
        }
    }
    __builtin_amdgcn_s_setprio(0);

#pragma unroll
    for (int r = 0; r < 4; ++r) {
        const int qloc = wl * 16 + lq * 4 + r;
        float p[4];
#pragma unroll
        for (int kb = 0; kb < 4; ++kb) {
            const bool msk = MASKED && (kb * 16 + lr > qloc);
            p[kb] = msk ? 0.0f : exp2f(s[kb][r]);
        }
        const unsigned int w0 = (unsigned int)f2b(p[0]) | ((unsigned int)f2b(p[1]) << 16);
        const unsigned int w1 = (unsigned int)f2b(p[2]) | ((unsigned int)f2b(p[3]) << 16);
        uint2 pk; pk.x = w0; pk.y = w1;
        *reinterpret_cast<uint2*>(&psw[lq * 4 + r][lr * 4]) = pk;
    }
    asm volatile("s_waitcnt lgkmcnt(0)" ::: "memory");
    __builtin_amdgcn_s_setprio(1);
#pragma unroll
    for (int ks = 0; ks < 2; ++ks) {
        const short8 pa = *reinterpret_cast<const short8*>(&psw[lr][ks * 32 + lq * 8]);
#pragma unroll
        for (int df = 0; df < 4; ++df) {
            const int vrow = df * 16 + lr;
            const int vch = (ks * 4 + lq) ^ (vrow & 7);
            const short8 vb = *reinterpret_cast<const short8*>(&vsb[vrow * 64 + vch * 8]);
            o[df] = __builtin_amdgcn_mfma_f32_16x16x32_bf16(pa, vb, o[df], 0, 0, 0);
        }
        o[4] = __builtin_amdgcn_mfma_f32_16x16x32_bf16(pa, vone, o[4], 0, 0, 0);
    }
    __builtin_amdgcn_s_setprio(0);
}

__global__ __launch_bounds__(512, 4) void attn_mfma(const unsigned short* __restrict__ QK,
                                                    const unsigned short* __restrict__ Vt,
                                                    unsigned short* __restrict__ Og)
{
    __shared__ __attribute__((aligned(128))) unsigned short Ks[2][64 * 64];
    __shared__ __attribute__((aligned(128))) unsigned short Vs[2][64 * 64];
    __shared__ __attribute__((aligned(16)))  unsigned short Ps[8][16][72];

    const int NQT = T_ / 128;
    const int px = blockIdx.x;
    const int qtA = px, qtB = NQT - 1 - px;
    const int h = blockIdx.y, b = blockIdx.z;
    const int tid = threadIdx.x, w = tid >> 6, l = tid & 63;
    const int wl = w & 3, qsub = w >> 2;
    const int lr = l & 15, lq = l >> 4;
    const size_t base = (size_t)b * T_ * QKS_ + h * HS_;

    short8 aqA[2], aqB[2];
    {
        const int qrl = qsub * 64 + wl * 16 + lr;
        const unsigned short* pA = QK + base + (size_t)(qtA * 128 + qrl) * QKS_;
        const unsigned short* pB = QK + base + (size_t)(qtB * 128 + qrl) * QKS_;
        aqA[0] = *reinterpret_cast<const short8*>(pA + lq * 8);
        aqA[1] = *reinterpret_cast<const short8*>(pA + 32 + lq * 8);
        aqB[0] = *reinterpret_cast<const short8*>(pB + lq * 8);
        aqB[1] = *reinterpret_cast<const short8*>(pB + 32 + lq * 8);
    }

    const unsigned short* Kg = QK + D_;
    const unsigned short* Vg = Vt + ((size_t)(b * H_ + h) * 64 << 11);   // [64 dims][T keys]

    auto stage = [&](int c, int bf) {
        const int kbase = c * 64;
        const int row = tid >> 3;
        const int cx = ((tid & 7) ^ (row & 7)) * 8;
        gload_lds16(Kg + base + (size_t)(kbase + row) * QKS_ + cx, &Ks[bf][tid * 8]);
        gload_lds16(Vg + ((size_t)row << 11) + kbase + cx, &Vs[bf][tid * 8]);
    };

    stage(0, 0);
    __syncthreads();

    unsigned short (*psw)[72] = Ps[w];

    f32x4 oA[5], oB[5];
#pragma unroll
    for (int df = 0; df < 5; ++df) {
        oA[df] = (f32x4){0.f, 0.f, 0.f, 0.f};
        oB[df] = (f32x4){0.f, 0.f, 0.f, 0.f};
    }

    const int qminw = qsub * 64 + wl * 16;
    const int qmaxw = qminw + 15;

    const int nch = 2 * qtB + 2;
    int bf = 0;
    for (int c = 0; c < nch; ++c) {
        if (c + 1 < nch) stage(c + 1, bf ^ 1);
        const int relA = c * 64 - qtA * 128;
        const int relB = c * 64 - qtB * 128;
        if (relA <= qmaxw) {
            if (relA + 63 <= qminw)
                attn_chunk<false>(&Ks[bf][0], &Vs[bf][0], psw, aqA, oA, lr, lq, wl);
            else
                attn_chunk<true>(&Ks[bf][0], &Vs[bf][0], psw, aqA, oA, lr, lq, wl);
        }
        if (relB <= qmaxw) {
            if (relB + 63 <= qminw)
                attn_chunk<false>(&Ks[bf][0], &Vs[bf][0], psw, aqB, oB, lr, lq, wl);
            else
                attn_chunk<true>(&Ks[bf][0], &Vs[bf][0], psw, aqB, oB, lr, lq, wl);
        }
        if (c + 1 < nch) __syncthreads();
        bf ^= 1;
    }

    const size_t obase = (size_t)b * T_ * D_ + h * HS_;
#pragma unroll
    for (int r = 0; r < 4; ++r) {
        const float invA = 1.0f / oA[4][r];
        const float invB = 1.0f / oB[4][r];
        const int qrl = qsub * 64 + wl * 16 + lq * 4 + r;
        unsigned short* orowA = Og + obase + (size_t)(qtA * 128 + qrl) * D_;
        unsigned short* orowB = Og + obase + (size_t)(qtB * 128 + qrl) * D_;
#pragma unroll
        for (int df = 0; df < 4; ++df) {
            orowA[df * 16 + lr] = f2b(oA[df][r] * invA);
            orowB[df * 16 + lr] = f2b(oB[df][r] * invB);
        }
    }
}

// ---------------- launcher ----------------
extern "C" void kernel_launch(void* const* d_in, const int* in_sizes, int n_in,
                              void* d_out, int out_size, void* d_ws, size_t ws_size,
                              hipStream_t stream)
{
    const float* x   = (const float*)d_in[0];
    const float* Wq  = (const float*)d_in[1];
    const float* Wk  = (const float*)d_in[2];
    const float* Wv  = (const float*)d_in[3];
    const float* Wo  = (const float*)d_in[4];
    const float* bo  = (const float*)d_in[5];
    const float* W1  = (const float*)d_in[6];
    const float* b1  = (const float*)d_in[7];
    const float* W2  = (const float*)d_in[8];
    const float* b2  = (const float*)d_in[9];
    const float* g1  = (const float*)d_in[10];
    const float* be1 = (const float*)d_in[11];
    const float* g2  = (const float*)d_in[12];
    const float* be2 = (const float*)d_in[13];
    float* out = (float*)d_out;

    unsigned short* ws = (unsigned short*)d_ws;
    const size_t NT = (size_t)B_ * T_;  // 8192
    unsigned short* hb    = ws;                        // NT*D
    unsigned short* QKb   = hb + NT * D_;              // NT*2D (within 4D region)
    unsigned short* Ab    = QKb + NT * 3 * D_;         // NT*D (region offset 3D)
    unsigned short* f1    = QKb;                       // NT*4D overlays QK+Ab
    unsigned short* Wtqkv = Ab + NT * D_;              // (3072,1024)
    unsigned short* Wto   = Wtqkv + (size_t)3 * D_ * D_;
    unsigned short* Wt1   = Wto + (size_t)D_ * D_;     // (4D, D)
    unsigned short* Wt2   = Wt1 + (size_t)4 * D_ * D_; // (D, 4D)
    unsigned short* Vtb   = Wt2 + (size_t)4 * D_ * D_; // (B*H*64, T) transposed V

    dim3 b256(256), b512(512);

    transpose_all<<<dim3(12288), b256, 0, stream>>>(Wq, Wk, Wv, Wo, W1, W2,
                                                    Wtqkv, Wto, Wt1, Wt2);

    ln_kernel<<<NT, b256, 0, stream>>>(x, g1, be1, hb);

    // QK: N=2048 on 256^2 kernel, grid 8x32 = 256 blocks (1 clean CU-wave)
    gemm_sq<false, false, false, true, true><<<dim3(2 * D_ / 256, NT / 256), b512, 0, stream>>>(
        hb, Wtqkv, nullptr, nullptr, nullptr, QKb, (int)NT, 2 * D_, D_);

    // V: N=1024, all blocks -> Vt (transposed+sigma), grid 4x64 = 256 blocks, 2 blk/CU
    gemm_sq2<false, false, false, false, false, true><<<dim3(D_ / 256, NT / 128), b512, 0, stream>>>(
        hb, Wtqkv + (size_t)2 * D_ * D_, nullptr, nullptr, nullptr, nullptr, Vtb, (int)NT, D_, D_);

    attn_mfma<<<dim3(T_ / 256, H_, B_), b512, 0, stream>>>(QKb, Vtb, Ab);

    // out = x + attn @ Wo + bo   (grid 4x64 = 256 blocks, 2 blk/CU)
    gemm_sq2<true, false, true, false, false, false><<<dim3(D_ / 256, NT / 128), b512, 0, stream>>>(
        Ab, Wto, bo, x, out, nullptr, nullptr, (int)NT, D_, D_);

    ln_kernel<<<NT, b256, 0, stream>>>(out, g2, be2, hb);

    // ffn1 = relu(h2 @ W1 + b1)  (grid 16x32 = 512 blocks, coalesced bf16 epilogue)
    gemm_sq<true, true, false, true, false><<<dim3(4 * D_ / 256, NT / 256), b512, 0, stream>>>(
        hb, Wt1, b1, nullptr, nullptr, f1, (int)NT, 4 * D_, D_);

    // out = out + ffn1 @ W2 + b2 (grid 4x64 = 256 blocks, K=4096, 2 blk/CU)
    gemm_sq2<true, false, true, false, false, false><<<dim3(D_ / 256, NT / 128), b512, 0, stream>>>(
        f1, Wt2, b2, out, out, nullptr, nullptr, (int)NT, D_, 4 * D_);
}

// Round 21
// 326.976 us; speedup vs baseline: 1.0583x; 1.0583x over previous
//
#include <hip/hip_runtime.h>
#include <hip/hip_bf16.h>
#include <cstddef>

#define B_ 4
#define T_ 2048
#define D_ 1024
#define H_ 16
#define HS_ 64
#define QKS_ 2048   // fused QK row stride

typedef short short8 __attribute__((ext_vector_type(8)));
typedef float f32x4 __attribute__((ext_vector_type(4)));

__device__ __forceinline__ unsigned short f2b(float x) {
    __hip_bfloat16 b = __float2bfloat16(x);
    return *reinterpret_cast<unsigned short*>(&b);
}

__device__ __forceinline__ void gload_lds16(const void* g, void* l) {
    __builtin_amdgcn_global_load_lds((const __attribute__((address_space(1))) void*)g,
                                     (__attribute__((address_space(3))) void*)l, 16, 0, 0);
}

// ---------------- LayerNorm: fp32 in -> bf16 out ----------------
__global__ __launch_bounds__(256) void ln_kernel(const float* __restrict__ X,
                                                 const float* __restrict__ g,
                                                 const float* __restrict__ be,
                                                 unsigned short* __restrict__ O)
{
    const int row = blockIdx.x;
    const int tid = threadIdx.x;
    const float* xr = X + (size_t)row * D_;
    float4 xv = *reinterpret_cast<const float4*>(xr + tid * 4);
    float s  = xv.x + xv.y + xv.z + xv.w;
    float s2 = xv.x * xv.x + xv.y * xv.y + xv.z * xv.z + xv.w * xv.w;
#pragma unroll
    for (int off = 32; off > 0; off >>= 1) {
        s  += __shfl_xor(s,  off);
        s2 += __shfl_xor(s2, off);
    }
    __shared__ float red[8];
    const int wid = tid >> 6, lane = tid & 63;
    if (lane == 0) { red[wid * 2] = s; red[wid * 2 + 1] = s2; }
    __syncthreads();
    s  = red[0] + red[2] + red[4] + red[6];
    s2 = red[1] + red[3] + red[5] + red[7];
    const float mu  = s * (1.0f / D_);
    const float var = s2 * (1.0f / D_) - mu * mu;
    const float r   = rsqrtf(var + 1e-5f);
    float4 gv = *reinterpret_cast<const float4*>(g  + tid * 4);
    float4 bv = *reinterpret_cast<const float4*>(be + tid * 4);
    ushort4 ov;
    ov.x = f2b((xv.x - mu) * r * gv.x + bv.x);
    ov.y = f2b((xv.y - mu) * r * gv.y + bv.y);
    ov.z = f2b((xv.z - mu) * r * gv.z + bv.z);
    ov.w = f2b((xv.w - mu) * r * gv.w + bv.w);
    *reinterpret_cast<ushort4*>(O + (size_t)row * D_ + tid * 4) = ov;
}

// ---------------- all weight transposes fused into one kernel ----------------
__global__ __launch_bounds__(256) void transpose_all(const float* __restrict__ Wq,
                                                     const float* __restrict__ Wk,
                                                     const float* __restrict__ Wv,
                                                     const float* __restrict__ Wo,
                                                     const float* __restrict__ W1,
                                                     const float* __restrict__ W2,
                                                     unsigned short* __restrict__ Wtqkv,
                                                     unsigned short* __restrict__ Wto,
                                                     unsigned short* __restrict__ Wt1,
                                                     unsigned short* __restrict__ Wt2)
{
    __shared__ float tile[32][33];
    const int tx = threadIdx.x & 31, ty = threadIdx.x >> 5;
    int s = blockIdx.x;

    if (s < 3072) {   // headed: out[noff+n][k] = in[n>>6][k][n&63]
        const float* in = (s < 1024) ? Wq : (s < 2048) ? Wk : Wv;
        const int noff = (s < 1024) ? 0 : (s < 2048) ? D_ : 2 * D_;
        s &= 1023;
        const int bn = (s & 31) * 32, bk = (s >> 5) * 32;
        const int head = bn >> 6, s0 = bn & 63;
#pragma unroll
        for (int i = 0; i < 32; i += 8)
            tile[ty + i][tx] = in[(size_t)head * D_ * HS_ + (size_t)(bk + ty + i) * HS_ + s0 + tx];
        __syncthreads();
#pragma unroll
        for (int i = 0; i < 32; i += 8)
            Wtqkv[(size_t)(noff + bn + ty + i) * D_ + bk + tx] = f2b(tile[tx][ty + i]);
        return;
    }
    s -= 3072;
    const float* in; unsigned short* out; int K, N, bn, bk;
    if (s < 1024)      { in = Wo; out = Wto; K = D_;     N = D_;     bn = (s & 31) * 32;  bk = (s >> 5) * 32; }
    else if (s < 5120) { s -= 1024; in = W1; out = Wt1; K = D_;     N = 4 * D_; bn = (s & 127) * 32; bk = (s >> 7) * 32; }
    else               { s -= 5120; in = W2; out = Wt2; K = 4 * D_; N = D_;     bn = (s & 31) * 32;  bk = (s >> 5) * 32; }
#pragma unroll
    for (int i = 0; i < 32; i += 8)
        tile[ty + i][tx] = in[(size_t)(bk + ty + i) * N + bn + tx];
    __syncthreads();
#pragma unroll
    for (int i = 0; i < 32; i += 8)
        out[(size_t)(bn + ty + i) * K + bk + tx] = f2b(tile[tx][ty + i]);
}

// ---------------- 256x256 bf16 MFMA GEMM, never-drain counted-vmcnt schedule ----------------
// Half-tiles (A0,B0,B1,A1 = 128x64 each) issued 5 phases ahead; per tile: vmcnt(4),
// 2 barriers, 4 phases x 16 MFMA. LDS content swizzle: chunk ci holds global ci^(row&7).
// OUT_BF16 epilogue goes through LDS for full-cache-line coalesced stores.
template<bool BIAS, bool RELU, bool RESID, bool OUT_BF16, bool SCALEQ>
__global__ __launch_bounds__(512, 1) void gemm_sq(const unsigned short* __restrict__ A,
                                                  const unsigned short* __restrict__ Bt,
                                                  const float* __restrict__ bias,
                                                  const float* __restrict__ resid,
                                                  float* __restrict__ Cf,
                                                  unsigned short* __restrict__ Cb,
                                                  int M, int N, int K)
{
    constexpr int BUFS = 16384 + 16384;   // shorts: A 256x64 + B 256x64
    __shared__ __attribute__((aligned(128))) unsigned short lds[2 * BUFS];

    const int tid = threadIdx.x, l = tid & 63, w = tid >> 6;
    const int wRow = w >> 2, wCol = w & 3;
    const int lr = l & 15, lq = l >> 4;

    const int gx = gridDim.x;
    const int nwg = gx * (int)gridDim.y;
    const int orig = (int)blockIdx.y * gx + (int)blockIdx.x;
    const int xcd = orig & 7, lo = orig >> 3;
    const int q8 = nwg >> 3, r8 = nwg & 7;
    const int wg = (xcd < r8 ? xcd * (q8 + 1) : r8 * (q8 + 1) + (xcd - r8) * q8) + lo;
    const int bm = wg / gx, bn = wg % gx;

    const int nt = K >> 6;

    // half: 0=A rows 0-127, 1=B rows 0-127, 2=B rows 128-255, 3=A rows 128-255
    auto ISSUE_HALF = [&](int t, int half) {
        const size_t kof = (size_t)t * 64;
        const int buf = t & 1;
        const bool isA = (half == 0) || (half == 3);
        const unsigned short* src = isA ? A : Bt;
        const int rb = (isA ? bm : bn) * 256 + ((half >= 2) ? 128 : 0);
        const int lb = buf * BUFS + (isA ? 0 : 16384) + ((half >= 2) ? 8192 : 0);
#pragma unroll
        for (int p = 0; p < 2; ++p) {
            const int j = p * 512 + tid;
            const int row = j >> 3, ci = j & 7;
            gload_lds16(src + (size_t)(rb + row) * K + kof + ((ci ^ (row & 7)) * 8),
                        &lds[lb + j * 8]);
        }
    };

    f32x4 acc[8][4];
#pragma unroll
    for (int i = 0; i < 8; ++i)
#pragma unroll
        for (int j = 0; j < 4; ++j) acc[i][j] = (f32x4){0.f, 0.f, 0.f, 0.f};

    short8 af[4][2], bf[4][2];
    const int swz = lr & 7;

    // prologue: tile 0 complete + tile 1's A0,B0
    ISSUE_HALF(0, 0); ISSUE_HALF(0, 1); ISSUE_HALF(0, 2); ISSUE_HALF(0, 3);
    if (nt > 1) { ISSUE_HALF(1, 0); ISSUE_HALF(1, 1); }

    for (int t = 0; t < nt; ++t) {
        const unsigned short* As = &lds[(t & 1) * BUFS];
        const unsigned short* Bs = As + 16384;

        if (t + 1 < nt) asm volatile("s_waitcnt vmcnt(4)" ::: "memory");
        else            asm volatile("s_waitcnt vmcnt(0)" ::: "memory");
        __builtin_amdgcn_s_barrier();          // tile t landed; prior-tenant reads done

        // ---- phase 0: issue B1(t+1); read af m0-3 + bf n0-1; MFMA (m0-3 x n0-1)
        if (t + 1 < nt) ISSUE_HALF(t + 1, 2);
#pragma unroll
        for (int mi = 0; mi < 4; ++mi) {
            const int row = wRow * 128 + mi * 16 + lr;
#pragma unroll
            for (int ks = 0; ks < 2; ++ks)
                af[mi][ks] = *reinterpret_cast<const short8*>(&As[row * 64 + (((ks * 4 + lq) ^ swz) * 8)]);
        }
#pragma unroll
        for (int nj = 0; nj < 2; ++nj) {
            const int rowB = wCol * 64 + nj * 16 + lr;
#pragma unroll
            for (int ks = 0; ks < 2; ++ks)
                bf[nj][ks] = *reinterpret_cast<const short8*>(&Bs[rowB * 64 + (((ks * 4 + lq) ^ swz) * 8)]);
        }
        asm volatile("s_waitcnt lgkmcnt(0)" ::: "memory");
        __builtin_amdgcn_sched_barrier(0);
        __builtin_amdgcn_s_setprio(1);
#pragma unroll
        for (int mi = 0; mi < 4; ++mi)
#pragma unroll
            for (int nj = 0; nj < 2; ++nj)
#pragma unroll
                for (int ks = 0; ks < 2; ++ks)
                    acc[mi][nj] = __builtin_amdgcn_mfma_f32_16x16x32_bf16(af[mi][ks], bf[nj][ks], acc[mi][nj], 0, 0, 0);
        __builtin_amdgcn_s_setprio(0);

        // ---- phase 1: issue A1(t+1); read bf n2-3; MFMA (m0-3 x n2-3)
        if (t + 1 < nt) ISSUE_HALF(t + 1, 3);
#pragma unroll
        for (int nj = 2; nj < 4; ++nj) {
            const int rowB = wCol * 64 + nj * 16 + lr;
#pragma unroll
            for (int ks = 0; ks < 2; ++ks)
                bf[nj][ks] = *reinterpret_cast<const short8*>(&Bs[rowB * 64 + (((ks * 4 + lq) ^ swz) * 8)]);
        }
        asm volatile("s_waitcnt lgkmcnt(0)" ::: "memory");
        __builtin_amdgcn_sched_barrier(0);
        __builtin_amdgcn_s_setprio(1);
#pragma unroll
        for (int mi = 0; mi < 4; ++mi)
#pragma unroll
            for (int nj = 2; nj < 4; ++nj)
#pragma unroll
                for (int ks = 0; ks < 2; ++ks)
                    acc[mi][nj] = __builtin_amdgcn_mfma_f32_16x16x32_bf16(af[mi][ks], bf[nj][ks], acc[mi][nj], 0, 0, 0);
        __builtin_amdgcn_s_setprio(0);

        // ---- phase 2: read af m4-7; MFMA (m4-7 x n0-1)
#pragma unroll
        for (int mi = 0; mi < 4; ++mi) {
            const int row = wRow * 128 + (4 + mi) * 16 + lr;
#pragma unroll
            for (int ks = 0; ks < 2; ++ks)
                af[mi][ks] = *reinterpret_cast<const short8*>(&As[row * 64 + (((ks * 4 + lq) ^ swz) * 8)]);
        }
        asm volatile("s_waitcnt lgkmcnt(0)" ::: "memory");
        __builtin_amdgcn_sched_barrier(0);
        __builtin_amdgcn_s_setprio(1);
#pragma unroll
        for (int mi = 0; mi < 4; ++mi)
#pragma unroll
            for (int nj = 0; nj < 2; ++nj)
#pragma unroll
                for (int ks = 0; ks < 2; ++ks)
                    acc[4 + mi][nj] = __builtin_amdgcn_mfma_f32_16x16x32_bf16(af[mi][ks], bf[nj][ks], acc[4 + mi][nj], 0, 0, 0);
        __builtin_amdgcn_s_setprio(0);

        __builtin_amdgcn_s_barrier();          // all tile-t LDS reads done

        // ---- phase 3: issue A0,B0(t+2) into buf[t&1]; MFMA (m4-7 x n2-3)
        if (t + 2 < nt) { ISSUE_HALF(t + 2, 0); ISSUE_HALF(t + 2, 1); }
        __builtin_amdgcn_s_setprio(1);
#pragma unroll
        for (int mi = 0; mi < 4; ++mi)
#pragma unroll
            for (int nj = 2; nj < 4; ++nj)
#pragma unroll
                for (int ks = 0; ks < 2; ++ks)
                    acc[4 + mi][nj] = __builtin_amdgcn_mfma_f32_16x16x32_bf16(af[mi][ks], bf[nj][ks], acc[4 + mi][nj], 0, 0, 0);
        __builtin_amdgcn_s_setprio(0);
    }

    const int m0 = bm * 256 + wRow * 128;
    const int n0 = bn * 256 + wCol * 64;
    if constexpr (OUT_BF16) {
        // coalesced epilogue: stage wave's 128x64 bf16 subtile in LDS, store 16B/lane
        __syncthreads();                           // all waves done with pipeline LDS
        unsigned short* ldsE = lds + w * 8192;     // [128 rows][64 cols]
#pragma unroll
        for (int nf = 0; nf < 4; ++nf) {
            const int col = n0 + nf * 16 + lr;
            const float bv = BIAS ? bias[col] : 0.0f;
#pragma unroll
            for (int mf = 0; mf < 8; ++mf) {
#pragma unroll
                for (int r = 0; r < 4; ++r) {
                    float c = acc[mf][nf][r] + bv;
                    if (RELU) c = fmaxf(c, 0.0f);
                    if (SCALEQ) { if (col < D_) c *= 0.18033688f; }
                    ldsE[(mf * 16 + lq * 4 + r) * 64 + nf * 16 + lr] = f2b(c);
                }
            }
        }
        asm volatile("s_waitcnt lgkmcnt(0)" ::: "memory");   // own-wave writes visible
        const int lg = l >> 3, lc = (l & 7) * 8;
#pragma unroll
        for (int i = 0; i < 16; ++i) {
            const int rowl = i * 8 + lg;
            short8 v = *reinterpret_cast<const short8*>(&ldsE[rowl * 64 + lc]);
            *reinterpret_cast<short8*>(&Cb[(size_t)(m0 + rowl) * N + n0 + lc]) = v;
        }
    } else {
#pragma unroll
        for (int nf = 0; nf < 4; ++nf) {
            const int col = n0 + nf * 16 + lr;
            const float bv = BIAS ? bias[col] : 0.0f;
#pragma unroll
            for (int mf = 0; mf < 8; ++mf) {
#pragma unroll
                for (int r = 0; r < 4; ++r) {
                    const int row = m0 + mf * 16 + lq * 4 + r;
                    float c = acc[mf][nf][r] + bv;
                    if (RELU) c = fmaxf(c, 0.0f);
                    if (RESID) c += resid[(size_t)row * N + col];
                    if (SCALEQ) { if (col < D_) c *= 0.18033688f; }
                    Cf[(size_t)row * N + col] = c;
                }
            }
        }
    }
}

// ---------------- 128(M)x256(N) bf16 MFMA GEMM, 3-buffer depth-2 pipeline ----------------
// (round-19 proven version, BK=64)
// VONLY: ALL blocks' 128x256 tiles are transposed THROUGH LDS (sigma at LDS-write) and
// stored coalesced to Vt[((b*16+head)*64+s)][(t&~63)+sigma(t&63)], sigma(k)=(k&15)*4+(k>>4).
template<bool BIAS, bool RELU, bool RESID, bool OUT_BF16, bool SCALEQ, bool VONLY>
__global__ __launch_bounds__(512, 1) void gemm_sq2(const unsigned short* __restrict__ A,
                                                   const unsigned short* __restrict__ Bt,
                                                   const float* __restrict__ bias,
                                                   const float* __restrict__ resid,
                                                   float* __restrict__ Cf,
                                                   unsigned short* __restrict__ Cb,
                                                   unsigned short* __restrict__ Vt,
                                                   int M, int N, int K)
{
    constexpr int BUFS = 8192 + 16384;   // shorts: A 128x64 + B 256x64
    __shared__ __attribute__((aligned(128))) unsigned short lds[3 * BUFS];

    const int tid = threadIdx.x, l = tid & 63, w = tid >> 6;
    const int wRow = w >> 2, wCol = w & 3;
    const int lr = l & 15, lq = l >> 4;

    const int gx = gridDim.x;
    const int nwg = gx * (int)gridDim.y;
    const int orig = (int)blockIdx.y * gx + (int)blockIdx.x;
    const int xcd = orig & 7, lo = orig >> 3;
    const int q8 = nwg >> 3, r8 = nwg & 7;
    const int wg = (xcd < r8 ? xcd * (q8 + 1) : r8 * (q8 + 1) + (xcd - r8) * q8) + lo;
    const int bm = wg / gx, bn = wg % gx;

    const int nt = K >> 6;

    auto ISSUE = [&](int t, int buf) {
        const size_t kof = (size_t)t * 64;
#pragma unroll
        for (int p = 0; p < 2; ++p) {          // A: 128 rows
            const int j = p * 512 + tid;
            const int row = j >> 3, ci = j & 7;
            gload_lds16(A + (size_t)(bm * 128 + row) * K + kof + ((ci ^ (row & 7)) * 8),
                        &lds[buf * BUFS + j * 8]);
        }
#pragma unroll
        for (int p = 0; p < 4; ++p) {          // B: 256 rows
            const int j = p * 512 + tid;
            const int row = j >> 3, ci = j & 7;
            gload_lds16(Bt + (size_t)(bn * 256 + row) * K + kof + ((ci ^ (row & 7)) * 8),
                        &lds[buf * BUFS + 8192 + j * 8]);
        }
    };

    f32x4 acc[4][4];
#pragma unroll
    for (int i = 0; i < 4; ++i)
#pragma unroll
        for (int j = 0; j < 4; ++j) acc[i][j] = (f32x4){0.f, 0.f, 0.f, 0.f};

    short8 af[2][2], bf[4][2];
    const int swz = lr & 7;

    ISSUE(0, 0);
    ISSUE(1, 1);

    for (int t = 0; t < nt; ++t) {
        const unsigned short* As = &lds[(t % 3) * BUFS];
        const unsigned short* Bs = As + 8192;
        if (t + 1 < nt) asm volatile("s_waitcnt vmcnt(6)" ::: "memory");
        else            asm volatile("s_waitcnt vmcnt(0)" ::: "memory");
        __builtin_amdgcn_s_barrier();
        if (t + 2 < nt) ISSUE(t + 2, (t + 2) % 3);

        // phase 0
#pragma unroll
        for (int mi = 0; mi < 2; ++mi) {
            const int row = wRow * 64 + mi * 16 + lr;
#pragma unroll
            for (int ks = 0; ks < 2; ++ks)
                af[mi][ks] = *reinterpret_cast<const short8*>(&As[row * 64 + (((ks * 4 + lq) ^ swz) * 8)]);
        }
#pragma unroll
        for (int nj = 0; nj < 4; ++nj) {
            const int rowB = wCol * 64 + nj * 16 + lr;
#pragma unroll
            for (int ks = 0; ks < 2; ++ks)
                bf[nj][ks] = *reinterpret_cast<const short8*>(&Bs[rowB * 64 + (((ks * 4 + lq) ^ swz) * 8)]);
        }
        asm volatile("s_waitcnt lgkmcnt(0)" ::: "memory");
        __builtin_amdgcn_sched_barrier(0);
        __builtin_amdgcn_s_setprio(1);
#pragma unroll
        for (int mi = 0; mi < 2; ++mi)
#pragma unroll
            for (int nj = 0; nj < 4; ++nj)
#pragma unroll
                for (int ks = 0; ks < 2; ++ks)
                    acc[mi][nj] = __builtin_amdgcn_mfma_f32_16x16x32_bf16(af[mi][ks], bf[nj][ks], acc[mi][nj], 0, 0, 0);
        __builtin_amdgcn_s_setprio(0);

        // phase 1
#pragma unroll
        for (int mi = 0; mi < 2; ++mi) {
            const int row = wRow * 64 + (2 + mi) * 16 + lr;
#pragma unroll
            for (int ks = 0; ks < 2; ++ks)
                af[mi][ks] = *reinterpret_cast<const short8*>(&As[row * 64 + (((ks * 4 + lq) ^ swz) * 8)]);
        }
        asm volatile("s_waitcnt lgkmcnt(0)" ::: "memory");
        __builtin_amdgcn_sched_barrier(0);
        __builtin_amdgcn_s_setprio(1);
#pragma unroll
        for (int mi = 0; mi < 2; ++mi)
#pragma unroll
            for (int nj = 0; nj < 4; ++nj)
#pragma unroll
                for (int ks = 0; ks < 2; ++ks)
                    acc[2 + mi][nj] = __builtin_amdgcn_mfma_f32_16x16x32_bf16(af[mi][ks], bf[nj][ks], acc[2 + mi][nj], 0, 0, 0);
        __builtin_amdgcn_s_setprio(0);
    }

    // ---- epilogue
    if (VONLY) {
        // transpose 128x256 tile through LDS, coalesced store to Vt.
        __syncthreads();                      // all waves done reading pipeline LDS
        unsigned short* ldsT = lds;           // [256 cols][136] shorts (16B-aligned rows)
        const int n0l = wCol * 64;
        const int m0l = wRow * 64;
#pragma unroll
        for (int nf = 0; nf < 4; ++nf) {
            const int cl = n0l + nf * 16 + lr;
#pragma unroll
            for (int mf = 0; mf < 4; ++mf) {
#pragma unroll
                for (int r = 0; r < 4; ++r) {
                    const int rl = m0l + mf * 16 + lq * 4 + r;
                    const int pos = (rl & 64) + (((rl & 15) << 2) | ((rl >> 4) & 3)); // sigma
                    ldsT[cl * 136 + pos] = f2b(acc[mf][nf][r]);
                }
            }
        }
        __syncthreads();
        const int rowT = tid >> 1, half = tid & 1;
        const int colV = bn * 256 + rowT;
        const int hd = colV >> 6, sdim = colV & 63;
        const int bb = bm >> 4;
        const int tt0 = (bm & 15) * 128 + half * 64;
        unsigned short* dst = Vt + (((size_t)(bb * H_ + hd) * 64 + sdim) << 11) + tt0;
        const unsigned short* srcl = &ldsT[rowT * 136 + half * 64];
#pragma unroll
        for (int i = 0; i < 8; ++i)
            *reinterpret_cast<short8*>(dst + i * 8) =
                *reinterpret_cast<const short8*>(srcl + i * 8);
        return;
    }

    const int m0 = bm * 128 + wRow * 64;
    const int n0 = bn * 256 + wCol * 64;
#pragma unroll
    for (int nf = 0; nf < 4; ++nf) {
        const int col = n0 + nf * 16 + lr;
        const float bv = BIAS ? bias[col] : 0.0f;
#pragma unroll
        for (int mf = 0; mf < 4; ++mf) {
#pragma unroll
            for (int r = 0; r < 4; ++r) {
                const int row = m0 + mf * 16 + lq * 4 + r;
                float c = acc[mf][nf][r] + bv;
                if (RELU) c = fmaxf(c, 0.0f);
                if (RESID) c += resid[(size_t)row * N + col];
                if (SCALEQ) { if (col < D_) c *= 0.18033688f; }
                if (OUT_BF16) Cb[(size_t)row * N + col] = f2b(c);
                else          Cf[(size_t)row * N + col] = c;
            }
        }
    }
}

// ---------------- MFMA flash attention: paired Q-tiles, shared K/V sweep ----------------
// UNNORMALIZED exp2 softmax; denom via ones-MFMA row-sum.
// Q/K from fused QK buffer (stride 2048, K at +1024); V pre-transposed+sigma in Vt.
template<bool MASKED>
__device__ __forceinline__ void attn_chunk(
    const unsigned short* __restrict__ ksb,           // Ks[bf] 64x64 (chunk-XOR content)
    const unsigned short* __restrict__ vsb,           // Vs[bf] 64x64 (chunk-XOR content, rows=dims)
    unsigned short (* __restrict__ psw)[72],          // this wave's P [16][72] (j-permuted cols)
    const short8* aq, f32x4* o,
    int lr, int lq, int wl)
{
    const short8 vone = {0x3F80, 0x3F80, 0x3F80, 0x3F80, 0x3F80, 0x3F80, 0x3F80, 0x3F80};
    f32x4 s[4];
#pragma unroll
    for (int kb = 0; kb < 4; ++kb) s[kb] = (f32x4){0.f, 0.f, 0.f, 0.f};
    __builtin_amdgcn_s_setprio(1);
#pragma unroll
    for (int kb = 0; kb < 4; ++kb) {
        if (MASKED && kb > wl) continue;
        const int row = kb * 16 + lr;
        const int sw = row & 7;
#pragma unroll
        for (int ks = 0; ks < 2; ++ks) {
            const int ch = (ks * 4 + lq) ^ sw;
            const short8 bk = *reinterpret_cast<const short8*>(&ksb[row * 64 + ch * 8]);
            s[kb] = __builtin_amdgcn_mfma_f32_16x16x32_bf16(aq[ks], bk, s[kb], 0, 0, 0);
        }
    }
    __builtin_amdgcn_s_setprio(0);

#pragma unroll
    for (int r = 0; r < 4; ++r) {
        const int qloc = wl * 16 + lq * 4 + r;
        float p[4];
#pragma unroll
        for (int kb = 0; kb < 4; ++kb) {
            const bool msk = MASKED && (kb * 16 + lr > qloc);
            p[kb] = msk ? 0.0f : exp2f(s[kb][r]);
        }
        const unsigned int w0 = (unsigned int)f2b(p[0]) | ((unsigned int)f2b(p[1]) << 16);
        const unsigned int w1 = (unsigned int)f2b(p[2]) | ((unsigned int)f2b(p[3]) << 16);
        uint2 pk; pk.x = w0; pk.y = w1;
        *reinterpret_cast<uint2*>(&psw[lq * 4 + r][lr * 4]) = pk;
    }
    asm volatile("s_waitcnt lgkmcnt(0)" ::: "memory");
    __builtin_amdgcn_s_setprio(1);
#pragma unroll
    for (int ks = 0; ks < 2; ++ks) {
        const short8 pa = *reinterpret_cast<const short8*>(&psw[lr][ks * 32 + lq * 8]);
#pragma unroll
        for (int df = 0; df < 4; ++df) {
            const int vrow = df * 16 + lr;
            const int vch = (ks * 4 + lq) ^ (vrow & 7);
            const short8 vb = *reinterpret_cast<const short8*>(&vsb[vrow * 64 + vch * 8]);
            o[df] = __builtin_amdgcn_mfma_f32_16x16x32_bf16(pa, vb, o[df], 0, 0, 0);
        }
        o[4] = __builtin_amdgcn_mfma_f32_16x16x32_bf16(pa, vone, o[4], 0, 0, 0);
    }
    __builtin_amdgcn_s_setprio(0);
}

__global__ __launch_bounds__(512, 4) void attn_mfma(const unsigned short* __restrict__ QK,
                                                    const unsigned short* __restrict__ Vt,
                                                    unsigned short* __restrict__ Og)
{
    __shared__ __attribute__((aligned(128))) unsigned short Ks[2][64 * 64];
    __shared__ __attribute__((aligned(128))) unsigned short Vs[2][64 * 64];
    __shared__ __attribute__((aligned(16)))  unsigned short Ps[8][16][72];

    const int NQT = T_ / 128;
    const int px = blockIdx.x;
    const int qtA = px, qtB = NQT - 1 - px;
    const int h = blockIdx.y, b = blockIdx.z;
    const int tid = threadIdx.x, w = tid >> 6, l = tid & 63;
    const int wl = w & 3, qsub = w >> 2;
    const int lr = l & 15, lq = l >> 4;
    const size_t base = (size_t)b * T_ * QKS_ + h * HS_;

    short8 aqA[2], aqB[2];
    {
        const int qrl = qsub * 64 + wl * 16 + lr;
        const unsigned short* pA = QK + base + (size_t)(qtA * 128 + qrl) * QKS_;
        const unsigned short* pB = QK + base + (size_t)(qtB * 128 + qrl) * QKS_;
        aqA[0] = *reinterpret_cast<const short8*>(pA + lq * 8);
        aqA[1] = *reinterpret_cast<const short8*>(pA + 32 + lq * 8);
        aqB[0] = *reinterpret_cast<const short8*>(pB + lq * 8);
        aqB[1] = *reinterpret_cast<const short8*>(pB + 32 + lq * 8);
    }

    const unsigned short* Kg = QK + D_;
    const unsigned short* Vg = Vt + ((size_t)(b * H_ + h) * 64 << 11);   // [64 dims][T keys]

    auto stage = [&](int c, int bf) {
        const int kbase = c * 64;
        const int row = tid >> 3;
        const int cx = ((tid & 7) ^ (row & 7)) * 8;
        gload_lds16(Kg + base + (size_t)(kbase + row) * QKS_ + cx, &Ks[bf][tid * 8]);
        gload_lds16(Vg + ((size_t)row << 11) + kbase + cx, &Vs[bf][tid * 8]);
    };

    stage(0, 0);
    __syncthreads();

    unsigned short (*psw)[72] = Ps[w];

    f32x4 oA[5], oB[5];
#pragma unroll
    for (int df = 0; df < 5; ++df) {
        oA[df] = (f32x4){0.f, 0.f, 0.f, 0.f};
        oB[df] = (f32x4){0.f, 0.f, 0.f, 0.f};
    }

    const int qminw = qsub * 64 + wl * 16;
    const int qmaxw = qminw + 15;

    const int nch = 2 * qtB + 2;
    int bf = 0;
    for (int c = 0; c < nch; ++c) {
        if (c + 1 < nch) stage(c + 1, bf ^ 1);
        const int relA = c * 64 - qtA * 128;
        const int relB = c * 64 - qtB * 128;
        if (relA <= qmaxw) {
            if (relA + 63 <= qminw)
                attn_chunk<false>(&Ks[bf][0], &Vs[bf][0], psw, aqA, oA, lr, lq, wl);
            else
                attn_chunk<true>(&Ks[bf][0], &Vs[bf][0], psw, aqA, oA, lr, lq, wl);
        }
        if (relB <= qmaxw) {
            if (relB + 63 <= qminw)
                attn_chunk<false>(&Ks[bf][0], &Vs[bf][0], psw, aqB, oB, lr, lq, wl);
            else
                attn_chunk<true>(&Ks[bf][0], &Vs[bf][0], psw, aqB, oB, lr, lq, wl);
        }
        if (c + 1 < nch) __syncthreads();
        bf ^= 1;
    }

    const size_t obase = (size_t)b * T_ * D_ + h * HS_;
#pragma unroll
    for (int r = 0; r < 4; ++r) {
        const float invA = 1.0f / oA[4][r];
        const float invB = 1.0f / oB[4][r];
        const int qrl = qsub * 64 + wl * 16 + lq * 4 + r;
        unsigned short* orowA = Og + obase + (size_t)(qtA * 128 + qrl) * D_;
        unsigned short* orowB = Og + obase + (size_t)(qtB * 128 + qrl) * D_;
#pragma unroll
        for (int df = 0; df < 4; ++df) {
            orowA[df * 16 + lr] = f2b(oA[df][r] * invA);
            orowB[df * 16 + lr] = f2b(oB[df][r] * invB);
        }
    }
}

// ---------------- launcher ----------------
extern "C" void kernel_launch(void* const* d_in, const int* in_sizes, int n_in,
                              void* d_out, int out_size, void* d_ws, size_t ws_size,
                              hipStream_t stream)
{
    const float* x   = (const float*)d_in[0];
    const float* Wq  = (const float*)d_in[1];
    const float* Wk  = (const float*)d_in[2];
    const float* Wv  = (const float*)d_in[3];
    const float* Wo  = (const float*)d_in[4];
    const float* bo  = (const float*)d_in[5];
    const float* W1  = (const float*)d_in[6];
    const float* b1  = (const float*)d_in[7];
    const float* W2  = (const float*)d_in[8];
    const float* b2  = (const float*)d_in[9];
    const float* g1  = (const float*)d_in[10];
    const float* be1 = (const float*)d_in[11];
    const float* g2  = (const float*)d_in[12];
    const float* be2 = (const float*)d_in[13];
    float* out = (float*)d_out;

    unsigned short* ws = (unsigned short*)d_ws;
    const size_t NT = (size_t)B_ * T_;  // 8192
    unsigned short* hb    = ws;                        // NT*D
    unsigned short* QKb   = hb + NT * D_;              // NT*2D (within 4D region)
    unsigned short* Ab    = QKb + NT * 3 * D_;         // NT*D (region offset 3D)
    unsigned short* f1    = QKb;                       // NT*4D overlays QK+Ab
    unsigned short* Wtqkv = Ab + NT * D_;              // (3072,1024)
    unsigned short* Wto   = Wtqkv + (size_t)3 * D_ * D_;
    unsigned short* Wt1   = Wto + (size_t)D_ * D_;     // (4D, D)
    unsigned short* Wt2   = Wt1 + (size_t)4 * D_ * D_; // (D, 4D)
    unsigned short* Vtb   = Wt2 + (size_t)4 * D_ * D_; // (B*H*64, T) transposed V

    dim3 b256(256), b512(512);

    transpose_all<<<dim3(12288), b256, 0, stream>>>(Wq, Wk, Wv, Wo, W1, W2,
                                                    Wtqkv, Wto, Wt1, Wt2);

    ln_kernel<<<NT, b256, 0, stream>>>(x, g1, be1, hb);

    // QK: N=2048 on 256^2 kernel, grid 8x32 = 256 blocks (1 clean CU-wave)
    gemm_sq<false, false, false, true, true><<<dim3(2 * D_ / 256, NT / 256), b512, 0, stream>>>(
        hb, Wtqkv, nullptr, nullptr, nullptr, QKb, (int)NT, 2 * D_, D_);

    // V: N=1024, all blocks -> Vt (transposed+sigma), grid 4x64 = 256 blocks
    gemm_sq2<false, false, false, false, false, true><<<dim3(D_ / 256, NT / 128), b512, 0, stream>>>(
        hb, Wtqkv + (size_t)2 * D_ * D_, nullptr, nullptr, nullptr, nullptr, Vtb, (int)NT, D_, D_);

    attn_mfma<<<dim3(T_ / 256, H_, B_), b512, 0, stream>>>(QKb, Vtb, Ab);

    // out = x + attn @ Wo + bo   (grid 4x64 = 256 blocks)
    gemm_sq2<true, false, true, false, false, false><<<dim3(D_ / 256, NT / 128), b512, 0, stream>>>(
        Ab, Wto, bo, x, out, nullptr, nullptr, (int)NT, D_, D_);

    ln_kernel<<<NT, b256, 0, stream>>>(out, g2, be2, hb);

    // ffn1 = relu(h2 @ W1 + b1)  (grid 16x32 = 512 blocks, coalesced bf16 epilogue)
    gemm_sq<true, true, false, true, false><<<dim3(4 * D_ / 256, NT / 256), b512, 0, stream>>>(
        hb, Wt1, b1, nullptr, nullptr, f1, (int)NT, 4 * D_, D_);

    // out = out + ffn1 @ W2 + b2 (grid 4x64 = 256 blocks, K=4096)
    gemm_sq2<true, false, true, false, false, false><<<dim3(D_ / 256, NT / 128), b512, 0, stream>>>(
        f1, Wt2, b2, out, out, nullptr, nullptr, (int)NT, D_, 4 * D_);
}

// Round 22
// 322.894 us; speedup vs baseline: 1.0716x; 1.0126x over previous
//
#include <hip/hip_runtime.h>
#include <hip/hip_bf16.h>
#include <cstddef>

#define B_ 4
#define T_ 2048
#define D_ 1024
#define H_ 16
#define HS_ 64
#define QKS_ 2048   // fused QK row stride

typedef short short8 __attribute__((ext_vector_type(8)));
typedef float f32x4 __attribute__((ext_vector_type(4)));

__device__ __forceinline__ unsigned short f2b(float x) {
    __hip_bfloat16 b = __float2bfloat16(x);
    return *reinterpret_cast<unsigned short*>(&b);
}

__device__ __forceinline__ void gload_lds16(const void* g, void* l) {
    __builtin_amdgcn_global_load_lds((const __attribute__((address_space(1))) void*)g,
                                     (__attribute__((address_space(3))) void*)l, 16, 0, 0);
}

// ---------------- LayerNorm: fp32 in -> bf16 out ----------------
__device__ __forceinline__ void ln_row(const float* __restrict__ X,
                                       const float* __restrict__ g,
                                       const float* __restrict__ be,
                                       unsigned short* __restrict__ O,
                                       int row, int tid, float* red)
{
    const float* xr = X + (size_t)row * D_;
    float4 xv = *reinterpret_cast<const float4*>(xr + tid * 4);
    float s  = xv.x + xv.y + xv.z + xv.w;
    float s2 = xv.x * xv.x + xv.y * xv.y + xv.z * xv.z + xv.w * xv.w;
#pragma unroll
    for (int off = 32; off > 0; off >>= 1) {
        s  += __shfl_xor(s,  off);
        s2 += __shfl_xor(s2, off);
    }
    const int wid = tid >> 6, lane = tid & 63;
    if (lane == 0) { red[wid * 2] = s; red[wid * 2 + 1] = s2; }
    __syncthreads();
    s  = red[0] + red[2] + red[4] + red[6];
    s2 = red[1] + red[3] + red[5] + red[7];
    const float mu  = s * (1.0f / D_);
    const float var = s2 * (1.0f / D_) - mu * mu;
    const float r   = rsqrtf(var + 1e-5f);
    float4 gv = *reinterpret_cast<const float4*>(g  + tid * 4);
    float4 bv = *reinterpret_cast<const float4*>(be + tid * 4);
    ushort4 ov;
    ov.x = f2b((xv.x - mu) * r * gv.x + bv.x);
    ov.y = f2b((xv.y - mu) * r * gv.y + bv.y);
    ov.z = f2b((xv.z - mu) * r * gv.z + bv.z);
    ov.w = f2b((xv.w - mu) * r * gv.w + bv.w);
    *reinterpret_cast<ushort4*>(O + (size_t)row * D_ + tid * 4) = ov;
}

__global__ __launch_bounds__(256) void ln_kernel(const float* __restrict__ X,
                                                 const float* __restrict__ g,
                                                 const float* __restrict__ be,
                                                 unsigned short* __restrict__ O)
{
    __shared__ float red[8];
    ln_row(X, g, be, O, blockIdx.x, threadIdx.x, red);
}

// ---------------- prolog: weight transposes + LN1 fused ----------------
// blocks [0,12288): transposes; [12288, 12288+8192): LN1 rows.
__global__ __launch_bounds__(256) void prolog_kernel(const float* __restrict__ Wq,
                                                     const float* __restrict__ Wk,
                                                     const float* __restrict__ Wv,
                                                     const float* __restrict__ Wo,
                                                     const float* __restrict__ W1,
                                                     const float* __restrict__ W2,
                                                     unsigned short* __restrict__ Wtqkv,
                                                     unsigned short* __restrict__ Wto,
                                                     unsigned short* __restrict__ Wt1,
                                                     unsigned short* __restrict__ Wt2,
                                                     const float* __restrict__ x,
                                                     const float* __restrict__ g1,
                                                     const float* __restrict__ be1,
                                                     unsigned short* __restrict__ hb)
{
    __shared__ float tile[32][33];
    __shared__ float red[8];
    const int tx = threadIdx.x & 31, ty = threadIdx.x >> 5;
    int s = blockIdx.x;

    if (s >= 12288) {   // LN1
        ln_row(x, g1, be1, hb, s - 12288, threadIdx.x, red);
        return;
    }

    if (s < 3072) {   // headed: out[noff+n][k] = in[n>>6][k][n&63]
        const float* in = (s < 1024) ? Wq : (s < 2048) ? Wk : Wv;
        const int noff = (s < 1024) ? 0 : (s < 2048) ? D_ : 2 * D_;
        s &= 1023;
        const int bn = (s & 31) * 32, bk = (s >> 5) * 32;
        const int head = bn >> 6, s0 = bn & 63;
#pragma unroll
        for (int i = 0; i < 32; i += 8)
            tile[ty + i][tx] = in[(size_t)head * D_ * HS_ + (size_t)(bk + ty + i) * HS_ + s0 + tx];
        __syncthreads();
#pragma unroll
        for (int i = 0; i < 32; i += 8)
            Wtqkv[(size_t)(noff + bn + ty + i) * D_ + bk + tx] = f2b(tile[tx][ty + i]);
        return;
    }
    s -= 3072;
    const float* in; unsigned short* out; int K, N, bn, bk;
    if (s < 1024)      { in = Wo; out = Wto; K = D_;     N = D_;     bn = (s & 31) * 32;  bk = (s >> 5) * 32; }
    else if (s < 5120) { s -= 1024; in = W1; out = Wt1; K = D_;     N = 4 * D_; bn = (s & 127) * 32; bk = (s >> 7) * 32; }
    else               { s -= 5120; in = W2; out = Wt2; K = 4 * D_; N = D_;     bn = (s & 31) * 32;  bk = (s >> 5) * 32; }
#pragma unroll
    for (int i = 0; i < 32; i += 8)
        tile[ty + i][tx] = in[(size_t)(bk + ty + i) * N + bn + tx];
    __syncthreads();
#pragma unroll
    for (int i = 0; i < 32; i += 8)
        out[(size_t)(bn + ty + i) * K + bk + tx] = f2b(tile[tx][ty + i]);
}

// ---------------- 256x256 bf16 MFMA GEMM, 4-phase interleaved staging ----------------
// OUT_BF16 epilogue goes through LDS for full-cache-line coalesced stores.
template<bool BIAS, bool RELU, bool RESID, bool OUT_BF16, bool SCALEQ>
__global__ __launch_bounds__(512, 1) void gemm_sq(const unsigned short* __restrict__ A,
                                                  const unsigned short* __restrict__ Bt,
                                                  const float* __restrict__ bias,
                                                  const float* __restrict__ resid,
                                                  float* __restrict__ Cf,
                                                  unsigned short* __restrict__ Cb,
                                                  int M, int N, int K)
{
    constexpr int BUFS = 16384 + 16384;   // shorts: A 256x64 + B 256x64
    __shared__ __attribute__((aligned(128))) unsigned short lds[2 * BUFS];

    const int tid = threadIdx.x, l = tid & 63, w = tid >> 6;
    const int wRow = w >> 2, wCol = w & 3;
    const int lr = l & 15, lq = l >> 4;

    const int gx = gridDim.x;
    const int nwg = gx * (int)gridDim.y;
    const int orig = (int)blockIdx.y * gx + (int)blockIdx.x;
    const int xcd = orig & 7, lo = orig >> 3;
    const int q8 = nwg >> 3, r8 = nwg & 7;
    const int wg = (xcd < r8 ? xcd * (q8 + 1) : r8 * (q8 + 1) + (xcd - r8) * q8) + lo;
    const int bm = wg / gx, bn = wg % gx;

    const int nt = K >> 6;

    auto ISSUE_HALF = [&](int t, int half) {
        const size_t kof = (size_t)t * 64;
        const int buf = t & 1;
        const unsigned short* src = (half < 2) ? A : Bt;
        const int rb = ((half < 2) ? bm : bn) * 256 + (half & 1) * 128;
        const int lb = buf * BUFS + ((half >= 2) ? 16384 : 0) + (half & 1) * 128 * 64;
#pragma unroll
        for (int p = 0; p < 2; ++p) {
            const int j = p * 512 + tid;
            const int row = j >> 3, ci = j & 7;
            gload_lds16(src + (size_t)(rb + row) * K + kof + ((ci ^ (row & 7)) * 8),
                        &lds[lb + j * 8]);
        }
    };

    f32x4 acc[8][4];
#pragma unroll
    for (int i = 0; i < 8; ++i)
#pragma unroll
        for (int j = 0; j < 4; ++j) acc[i][j] = (f32x4){0.f, 0.f, 0.f, 0.f};

    short8 af[4][2], bf[4][2];
    const int swz = lr & 7;

#pragma unroll
    for (int h = 0; h < 4; ++h) ISSUE_HALF(0, h);

    for (int t = 0; t < nt; ++t) {
        const unsigned short* As = &lds[(t & 1) * BUFS];
        const unsigned short* Bs = As + 16384;
        const bool more = (t + 1 < nt);

        asm volatile("s_waitcnt vmcnt(0)" ::: "memory");
        __builtin_amdgcn_s_barrier();

        if (more) ISSUE_HALF(t + 1, 0);
#pragma unroll
        for (int mi = 0; mi < 4; ++mi) {
            const int row = wRow * 128 + mi * 16 + lr;
#pragma unroll
            for (int ks = 0; ks < 2; ++ks)
                af[mi][ks] = *reinterpret_cast<const short8*>(&As[row * 64 + (((ks * 4 + lq) ^ swz) * 8)]);
        }
#pragma unroll
        for (int nj = 0; nj < 2; ++nj) {
            const int rowB = wCol * 64 + nj * 16 + lr;
#pragma unroll
            for (int ks = 0; ks < 2; ++ks)
                bf[nj][ks] = *reinterpret_cast<const short8*>(&Bs[rowB * 64 + (((ks * 4 + lq) ^ swz) * 8)]);
        }
        asm volatile("s_waitcnt lgkmcnt(0)" ::: "memory");
        __builtin_amdgcn_sched_barrier(0);
        __builtin_amdgcn_s_setprio(1);
#pragma unroll
        for (int mi = 0; mi < 4; ++mi)
#pragma unroll
            for (int nj = 0; nj < 2; ++nj)
#pragma unroll
                for (int ks = 0; ks < 2; ++ks)
                    acc[mi][nj] = __builtin_amdgcn_mfma_f32_16x16x32_bf16(af[mi][ks], bf[nj][ks], acc[mi][nj], 0, 0, 0);
        __builtin_amdgcn_s_setprio(0);

        if (more) ISSUE_HALF(t + 1, 1);
#pragma unroll
        for (int nj = 2; nj < 4; ++nj) {
            const int rowB = wCol * 64 + nj * 16 + lr;
#pragma unroll
            for (int ks = 0; ks < 2; ++ks)
                bf[nj][ks] = *reinterpret_cast<const short8*>(&Bs[rowB * 64 + (((ks * 4 + lq) ^ swz) * 8)]);
        }
        asm volatile("s_waitcnt lgkmcnt(0)" ::: "memory");
        __builtin_amdgcn_sched_barrier(0);
        __builtin_amdgcn_s_setprio(1);
#pragma unroll
        for (int mi = 0; mi < 4; ++mi)
#pragma unroll
            for (int nj = 2; nj < 4; ++nj)
#pragma unroll
                for (int ks = 0; ks < 2; ++ks)
                    acc[mi][nj] = __builtin_amdgcn_mfma_f32_16x16x32_bf16(af[mi][ks], bf[nj][ks], acc[mi][nj], 0, 0, 0);
        __builtin_amdgcn_s_setprio(0);

        if (more) { ISSUE_HALF(t + 1, 2); ISSUE_HALF(t + 1, 3); }
#pragma unroll
        for (int mi = 0; mi < 4; ++mi) {
            const int row = wRow * 128 + (4 + mi) * 16 + lr;
#pragma unroll
            for (int ks = 0; ks < 2; ++ks)
                af[mi][ks] = *reinterpret_cast<const short8*>(&As[row * 64 + (((ks * 4 + lq) ^ swz) * 8)]);
        }
        asm volatile("s_waitcnt lgkmcnt(0)" ::: "memory");
        __builtin_amdgcn_sched_barrier(0);
        __builtin_amdgcn_s_setprio(1);
#pragma unroll
        for (int mi = 0; mi < 4; ++mi)
#pragma unroll
            for (int nj = 0; nj < 2; ++nj)
#pragma unroll
                for (int ks = 0; ks < 2; ++ks)
                    acc[4 + mi][nj] = __builtin_amdgcn_mfma_f32_16x16x32_bf16(af[mi][ks], bf[nj][ks], acc[4 + mi][nj], 0, 0, 0);
        __builtin_amdgcn_s_setprio(0);

        __builtin_amdgcn_s_setprio(1);
#pragma unroll
        for (int mi = 0; mi < 4; ++mi)
#pragma unroll
            for (int nj = 2; nj < 4; ++nj)
#pragma unroll
                for (int ks = 0; ks < 2; ++ks)
                    acc[4 + mi][nj] = __builtin_amdgcn_mfma_f32_16x16x32_bf16(af[mi][ks], bf[nj][ks], acc[4 + mi][nj], 0, 0, 0);
        __builtin_amdgcn_s_setprio(0);
    }

    const int m0 = bm * 256 + wRow * 128;
    const int n0 = bn * 256 + wCol * 64;
    if constexpr (OUT_BF16) {
        // coalesced epilogue: stage wave's 128x64 bf16 subtile in LDS, store 16B/lane
        __syncthreads();                           // all waves done with pipeline LDS
        unsigned short* ldsE = lds + w * 8192;     // [128 rows][64 cols]
#pragma unroll
        for (int nf = 0; nf < 4; ++nf) {
            const int col = n0 + nf * 16 + lr;
            const float bv = BIAS ? bias[col] : 0.0f;
#pragma unroll
            for (int mf = 0; mf < 8; ++mf) {
#pragma unroll
                for (int r = 0; r < 4; ++r) {
                    float c = acc[mf][nf][r] + bv;
                    if (RELU) c = fmaxf(c, 0.0f);
                    if (SCALEQ) { if (col < D_) c *= 0.18033688f; }
                    ldsE[(mf * 16 + lq * 4 + r) * 64 + nf * 16 + lr] = f2b(c);
                }
            }
        }
        asm volatile("s_waitcnt lgkmcnt(0)" ::: "memory");   // own-wave writes visible
        const int lg = l >> 3, lc = (l & 7) * 8;
#pragma unroll
        for (int i = 0; i < 16; ++i) {
            const int rowl = i * 8 + lg;
            short8 v = *reinterpret_cast<const short8*>(&ldsE[rowl * 64 + lc]);
            *reinterpret_cast<short8*>(&Cb[(size_t)(m0 + rowl) * N + n0 + lc]) = v;
        }
    } else {
#pragma unroll
        for (int nf = 0; nf < 4; ++nf) {
            const int col = n0 + nf * 16 + lr;
            const float bv = BIAS ? bias[col] : 0.0f;
#pragma unroll
            for (int mf = 0; mf < 8; ++mf) {
#pragma unroll
                for (int r = 0; r < 4; ++r) {
                    const int row = m0 + mf * 16 + lq * 4 + r;
                    float c = acc[mf][nf][r] + bv;
                    if (RELU) c = fmaxf(c, 0.0f);
                    if (RESID) c += resid[(size_t)row * N + col];
                    if (SCALEQ) { if (col < D_) c *= 0.18033688f; }
                    Cf[(size_t)row * N + col] = c;
                }
            }
        }
    }
}

// ---------------- 128(M)x256(N) bf16 MFMA GEMM, 3-buffer depth-2 pipeline ----------------
// VONLY: ALL blocks' 128x256 tiles are transposed THROUGH LDS (sigma at LDS-write) and
// stored coalesced to Vt[((b*16+head)*64+s)][(t&~63)+sigma(t&63)], sigma(k)=(k&15)*4+(k>>4).
template<bool BIAS, bool RELU, bool RESID, bool OUT_BF16, bool SCALEQ, bool VONLY>
__global__ __launch_bounds__(512, 1) void gemm_sq2(const unsigned short* __restrict__ A,
                                                   const unsigned short* __restrict__ Bt,
                                                   const float* __restrict__ bias,
                                                   const float* __restrict__ resid,
                                                   float* __restrict__ Cf,
                                                   unsigned short* __restrict__ Cb,
                                                   unsigned short* __restrict__ Vt,
                                                   int M, int N, int K)
{
    constexpr int BUFS = 8192 + 16384;   // shorts: A 128x64 + B 256x64
    __shared__ __attribute__((aligned(128))) unsigned short lds[3 * BUFS];

    const int tid = threadIdx.x, l = tid & 63, w = tid >> 6;
    const int wRow = w >> 2, wCol = w & 3;
    const int lr = l & 15, lq = l >> 4;

    const int gx = gridDim.x;
    const int nwg = gx * (int)gridDim.y;
    const int orig = (int)blockIdx.y * gx + (int)blockIdx.x;
    const int xcd = orig & 7, lo = orig >> 3;
    const int q8 = nwg >> 3, r8 = nwg & 7;
    const int wg = (xcd < r8 ? xcd * (q8 + 1) : r8 * (q8 + 1) + (xcd - r8) * q8) + lo;
    const int bm = wg / gx, bn = wg % gx;

    const int nt = K >> 6;

    auto ISSUE = [&](int t, int buf) {
        const size_t kof = (size_t)t * 64;
#pragma unroll
        for (int p = 0; p < 2; ++p) {          // A: 128 rows
            const int j = p * 512 + tid;
            const int row = j >> 3, ci = j & 7;
            gload_lds16(A + (size_t)(bm * 128 + row) * K + kof + ((ci ^ (row & 7)) * 8),
                        &lds[buf * BUFS + j * 8]);
        }
#pragma unroll
        for (int p = 0; p < 4; ++p) {          // B: 256 rows
            const int j = p * 512 + tid;
            const int row = j >> 3, ci = j & 7;
            gload_lds16(Bt + (size_t)(bn * 256 + row) * K + kof + ((ci ^ (row & 7)) * 8),
                        &lds[buf * BUFS + 8192 + j * 8]);
        }
    };

    f32x4 acc[4][4];
#pragma unroll
    for (int i = 0; i < 4; ++i)
#pragma unroll
        for (int j = 0; j < 4; ++j) acc[i][j] = (f32x4){0.f, 0.f, 0.f, 0.f};

    short8 af[2][2], bf[4][2];
    const int swz = lr & 7;

    ISSUE(0, 0);
    ISSUE(1, 1);

    for (int t = 0; t < nt; ++t) {
        const unsigned short* As = &lds[(t % 3) * BUFS];
        const unsigned short* Bs = As + 8192;
        if (t + 1 < nt) asm volatile("s_waitcnt vmcnt(6)" ::: "memory");
        else            asm volatile("s_waitcnt vmcnt(0)" ::: "memory");
        __builtin_amdgcn_s_barrier();
        if (t + 2 < nt) ISSUE(t + 2, (t + 2) % 3);

        // phase 0
#pragma unroll
        for (int mi = 0; mi < 2; ++mi) {
            const int row = wRow * 64 + mi * 16 + lr;
#pragma unroll
            for (int ks = 0; ks < 2; ++ks)
                af[mi][ks] = *reinterpret_cast<const short8*>(&As[row * 64 + (((ks * 4 + lq) ^ swz) * 8)]);
        }
#pragma unroll
        for (int nj = 0; nj < 4; ++nj) {
            const int rowB = wCol * 64 + nj * 16 + lr;
#pragma unroll
            for (int ks = 0; ks < 2; ++ks)
                bf[nj][ks] = *reinterpret_cast<const short8*>(&Bs[rowB * 64 + (((ks * 4 + lq) ^ swz) * 8)]);
        }
        asm volatile("s_waitcnt lgkmcnt(0)" ::: "memory");
        __builtin_amdgcn_sched_barrier(0);
        __builtin_amdgcn_s_setprio(1);
#pragma unroll
        for (int mi = 0; mi < 2; ++mi)
#pragma unroll
            for (int nj = 0; nj < 4; ++nj)
#pragma unroll
                for (int ks = 0; ks < 2; ++ks)
                    acc[mi][nj] = __builtin_amdgcn_mfma_f32_16x16x32_bf16(af[mi][ks], bf[nj][ks], acc[mi][nj], 0, 0, 0);
        __builtin_amdgcn_s_setprio(0);

        // phase 1
#pragma unroll
        for (int mi = 0; mi < 2; ++mi) {
            const int row = wRow * 64 + (2 + mi) * 16 + lr;
#pragma unroll
            for (int ks = 0; ks < 2; ++ks)
                af[mi][ks] = *reinterpret_cast<const short8*>(&As[row * 64 + (((ks * 4 + lq) ^ swz) * 8)]);
        }
        asm volatile("s_waitcnt lgkmcnt(0)" ::: "memory");
        __builtin_amdgcn_sched_barrier(0);
        __builtin_amdgcn_s_setprio(1);
#pragma unroll
        for (int mi = 0; mi < 2; ++mi)
#pragma unroll
            for (int nj = 0; nj < 4; ++nj)
#pragma unroll
                for (int ks = 0; ks < 2; ++ks)
                    acc[2 + mi][nj] = __builtin_amdgcn_mfma_f32_16x16x32_bf16(af[mi][ks], bf[nj][ks], acc[2 + mi][nj], 0, 0, 0);
        __builtin_amdgcn_s_setprio(0);
    }

    // ---- epilogue
    if (VONLY) {
        // transpose 128x256 tile through LDS, coalesced store to Vt.
        __syncthreads();                      // all waves done reading pipeline LDS
        unsigned short* ldsT = lds;           // [256 cols][136] shorts (16B-aligned rows)
        const int n0l = wCol * 64;
        const int m0l = wRow * 64;
#pragma unroll
        for (int nf = 0; nf < 4; ++nf) {
            const int cl = n0l + nf * 16 + lr;
#pragma unroll
            for (int mf = 0; mf < 4; ++mf) {
#pragma unroll
                for (int r = 0; r < 4; ++r) {
                    const int rl = m0l + mf * 16 + lq * 4 + r;
                    const int pos = (rl & 64) + (((rl & 15) << 2) | ((rl >> 4) & 3)); // sigma
                    ldsT[cl * 136 + pos] = f2b(acc[mf][nf][r]);
                }
            }
        }
        __syncthreads();
        const int rowT = tid >> 1, half = tid & 1;
        const int colV = bn * 256 + rowT;
        const int hd = colV >> 6, sdim = colV & 63;
        const int bb = bm >> 4;
        const int tt0 = (bm & 15) * 128 + half * 64;
        unsigned short* dst = Vt + (((size_t)(bb * H_ + hd) * 64 + sdim) << 11) + tt0;
        const unsigned short* srcl = &ldsT[rowT * 136 + half * 64];
#pragma unroll
        for (int i = 0; i < 8; ++i)
            *reinterpret_cast<short8*>(dst + i * 8) =
                *reinterpret_cast<const short8*>(srcl + i * 8);
        return;
    }

    const int m0 = bm * 128 + wRow * 64;
    const int n0 = bn * 256 + wCol * 64;
#pragma unroll
    for (int nf = 0; nf < 4; ++nf) {
        const int col = n0 + nf * 16 + lr;
        const float bv = BIAS ? bias[col] : 0.0f;
#pragma unroll
        for (int mf = 0; mf < 4; ++mf) {
#pragma unroll
            for (int r = 0; r < 4; ++r) {
                const int row = m0 + mf * 16 + lq * 4 + r;
                float c = acc[mf][nf][r] + bv;
                if (RELU) c = fmaxf(c, 0.0f);
                if (RESID) c += resid[(size_t)row * N + col];
                if (SCALEQ) { if (col < D_) c *= 0.18033688f; }
                if (OUT_BF16) Cb[(size_t)row * N + col] = f2b(c);
                else          Cf[(size_t)row * N + col] = c;
            }
        }
    }
}

// ---------------- MFMA flash attention: paired Q-tiles, shared K/V sweep ----------------
// UNNORMALIZED exp2 softmax; denom via ones-MFMA row-sum.
// Q/K from fused QK buffer (stride 2048, K at +1024); V pre-transposed+sigma in Vt.
template<bool MASKED>
__device__ __forceinline__ void attn_chunk(
    const unsigned short* __restrict__ ksb,           // Ks[bf] 64x64 (chunk-XOR content)
    const unsigned short* __restrict__ vsb,           // Vs[bf] 64x64 (chunk-XOR content, rows=dims)
    unsigned short (* __restrict__ psw)[72],          // this wave's P [16][72] (j-permuted cols)
    const short8* aq, f32x4* o,
    int lr, int lq, int wl)
{
    const short8 vone = {0x3F80, 0x3F80, 0x3F80, 0x3F80, 0x3F80, 0x3F80, 0x3F80, 0x3F80};
    f32x4 s[4];
#pragma unroll
    for (int kb = 0; kb < 4; ++kb) s[kb] = (f32x4){0.f, 0.f, 0.f, 0.f};
    __builtin_amdgcn_s_setprio(1);
#pragma unroll
    for (int kb = 0; kb < 4; ++kb) {
        if (MASKED && kb > wl) continue;
        const int row = kb * 16 + lr;
        const int sw = row & 7;
#pragma unroll
        for (int ks = 0; ks < 2; ++ks) {
            const int ch = (ks * 4 + lq) ^ sw;
            const short8 bk = *reinterpret_cast<const short8*>(&ksb[row * 64 + ch * 8]);
            s[kb] = __builtin_amdgcn_mfma_f32_16x16x32_bf16(aq[ks], bk, s[kb], 0, 0, 0);
        }
    }
    __builtin_amdgcn_s_setprio(0);

#pragma unroll
    for (int r = 0; r < 4; ++r) {
        const int qloc = wl * 16 + lq * 4 + r;
        float p[4];
#pragma unroll
        for (int kb = 0; kb < 4; ++kb) {
            const bool msk = MASKED && (kb * 16 + lr > qloc);
            p[kb] = msk ? 0.0f : exp2f(s[kb][r]);
        }
        const unsigned int w0 = (unsigned int)f2b(p[0]) | ((unsigned int)f2b(p[1]) << 16);
        const unsigned int w1 = (unsigned int)f2b(p[2]) | ((unsigned int)f2b(p[3]) << 16);
        uint2 pk; pk.x = w0; pk.y = w1;
        *reinterpret_cast<uint2*>(&psw[lq * 4 + r][lr * 4]) = pk;
    }
    asm volatile("s_waitcnt lgkmcnt(0)" ::: "memory");
    __builtin_amdgcn_s_setprio(1);
#pragma unroll
    for (int ks = 0; ks < 2; ++ks) {
        const short8 pa = *reinterpret_cast<const short8*>(&psw[lr][ks * 32 + lq * 8]);
#pragma unroll
        for (int df = 0; df < 4; ++df) {
            const int vrow = df * 16 + lr;
            const int vch = (ks * 4 + lq) ^ (vrow & 7);
            const short8 vb = *reinterpret_cast<const short8*>(&vsb[vrow * 64 + vch * 8]);
            o[df] = __builtin_amdgcn_mfma_f32_16x16x32_bf16(pa, vb, o[df], 0, 0, 0);
        }
        o[4] = __builtin_amdgcn_mfma_f32_16x16x32_bf16(pa, vone, o[4], 0, 0, 0);
    }
    __builtin_amdgcn_s_setprio(0);
}

__global__ __launch_bounds__(512, 4) void attn_mfma(const unsigned short* __restrict__ QK,
                                                    const unsigned short* __restrict__ Vt,
                                                    unsigned short* __restrict__ Og)
{
    __shared__ __attribute__((aligned(128))) unsigned short Ks[2][64 * 64];
    __shared__ __attribute__((aligned(128))) unsigned short Vs[2][64 * 64];
    __shared__ __attribute__((aligned(16)))  unsigned short Ps[8][16][72];

    const int NQT = T_ / 128;
    const int px = blockIdx.x;
    const int qtA = px, qtB = NQT - 1 - px;
    const int h = blockIdx.y, b = blockIdx.z;
    const int tid = threadIdx.x, w = tid >> 6, l = tid & 63;
    const int wl = w & 3, qsub = w >> 2;
    const int lr = l & 15, lq = l >> 4;
    const size_t base = (size_t)b * T_ * QKS_ + h * HS_;

    short8 aqA[2], aqB[2];
    {
        const int qrl = qsub * 64 + wl * 16 + lr;
        const unsigned short* pA = QK + base + (size_t)(qtA * 128 + qrl) * QKS_;
        const unsigned short* pB = QK + base + (size_t)(qtB * 128 + qrl) * QKS_;
        aqA[0] = *reinterpret_cast<const short8*>(pA + lq * 8);
        aqA[1] = *reinterpret_cast<const short8*>(pA + 32 + lq * 8);
        aqB[0] = *reinterpret_cast<const short8*>(pB + lq * 8);
        aqB[1] = *reinterpret_cast<const short8*>(pB + 32 + lq * 8);
    }

    const unsigned short* Kg = QK + D_;
    const unsigned short* Vg = Vt + ((size_t)(b * H_ + h) * 64 << 11);   // [64 dims][T keys]

    auto stage = [&](int c, int bf) {
        const int kbase = c * 64;
        const int row = tid >> 3;
        const int cx = ((tid & 7) ^ (row & 7)) * 8;
        gload_lds16(Kg + base + (size_t)(kbase + row) * QKS_ + cx, &Ks[bf][tid * 8]);
        gload_lds16(Vg + ((size_t)row << 11) + kbase + cx, &Vs[bf][tid * 8]);
    };

    stage(0, 0);
    __syncthreads();

    unsigned short (*psw)[72] = Ps[w];

    f32x4 oA[5], oB[5];
#pragma unroll
    for (int df = 0; df < 5; ++df) {
        oA[df] = (f32x4){0.f, 0.f, 0.f, 0.f};
        oB[df] = (f32x4){0.f, 0.f, 0.f, 0.f};
    }

    const int qminw = qsub * 64 + wl * 16;
    const int qmaxw = qminw + 15;

    const int nch = 2 * qtB + 2;
    int bf = 0;
    for (int c = 0; c < nch; ++c) {
        if (c + 1 < nch) stage(c + 1, bf ^ 1);
        const int relA = c * 64 - qtA * 128;
        const int relB = c * 64 - qtB * 128;
        if (relA <= qmaxw) {
            if (relA + 63 <= qminw)
                attn_chunk<false>(&Ks[bf][0], &Vs[bf][0], psw, aqA, oA, lr, lq, wl);
            else
                attn_chunk<true>(&Ks[bf][0], &Vs[bf][0], psw, aqA, oA, lr, lq, wl);
        }
        if (relB <= qmaxw) {
            if (relB + 63 <= qminw)
                attn_chunk<false>(&Ks[bf][0], &Vs[bf][0], psw, aqB, oB, lr, lq, wl);
            else
                attn_chunk<true>(&Ks[bf][0], &Vs[bf][0], psw, aqB, oB, lr, lq, wl);
        }
        if (c + 1 < nch) __syncthreads();
        bf ^= 1;
    }

    const size_t obase = (size_t)b * T_ * D_ + h * HS_;
#pragma unroll
    for (int r = 0; r < 4; ++r) {
        const float invA = 1.0f / oA[4][r];
        const float invB = 1.0f / oB[4][r];
        const int qrl = qsub * 64 + wl * 16 + lq * 4 + r;
        unsigned short* orowA = Og + obase + (size_t)(qtA * 128 + qrl) * D_;
        unsigned short* orowB = Og + obase + (size_t)(qtB * 128 + qrl) * D_;
#pragma unroll
        for (int df = 0; df < 4; ++df) {
            orowA[df * 16 + lr] = f2b(oA[df][r] * invA);
            orowB[df * 16 + lr] = f2b(oB[df][r] * invB);
        }
    }
}

// ---------------- launcher ----------------
extern "C" void kernel_launch(void* const* d_in, const int* in_sizes, int n_in,
                              void* d_out, int out_size, void* d_ws, size_t ws_size,
                              hipStream_t stream)
{
    const float* x   = (const float*)d_in[0];
    const float* Wq  = (const float*)d_in[1];
    const float* Wk  = (const float*)d_in[2];
    const float* Wv  = (const float*)d_in[3];
    const float* Wo  = (const float*)d_in[4];
    const float* bo  = (const float*)d_in[5];
    const float* W1  = (const float*)d_in[6];
    const float* b1  = (const float*)d_in[7];
    const float* W2  = (const float*)d_in[8];
    const float* b2  = (const float*)d_in[9];
    const float* g1  = (const float*)d_in[10];
    const float* be1 = (const float*)d_in[11];
    const float* g2  = (const float*)d_in[12];
    const float* be2 = (const float*)d_in[13];
    float* out = (float*)d_out;

    unsigned short* ws = (unsigned short*)d_ws;
    const size_t NT = (size_t)B_ * T_;  // 8192
    unsigned short* hb    = ws;                        // NT*D
    unsigned short* QKb   = hb + NT * D_;              // NT*2D (within 4D region)
    unsigned short* Ab    = QKb + NT * 3 * D_;         // NT*D (region offset 3D)
    unsigned short* f1    = QKb;                       // NT*4D overlays QK+Ab
    unsigned short* Wtqkv = Ab + NT * D_;              // (3072,1024)
    unsigned short* Wto   = Wtqkv + (size_t)3 * D_ * D_;
    unsigned short* Wt1   = Wto + (size_t)D_ * D_;     // (4D, D)
    unsigned short* Wt2   = Wt1 + (size_t)4 * D_ * D_; // (D, 4D)
    unsigned short* Vtb   = Wt2 + (size_t)4 * D_ * D_; // (B*H*64, T) transposed V

    dim3 b256(256), b512(512);

    // fused: weight transposes (12288 blocks) + LN1 (8192 blocks)
    prolog_kernel<<<dim3(12288 + 8192), b256, 0, stream>>>(
        Wq, Wk, Wv, Wo, W1, W2, Wtqkv, Wto, Wt1, Wt2, x, g1, be1, hb);

    // QK: N=2048 on 256^2 kernel, grid 8x32 = 256 blocks (1 clean CU-wave)
    gemm_sq<false, false, false, true, true><<<dim3(2 * D_ / 256, NT / 256), b512, 0, stream>>>(
        hb, Wtqkv, nullptr, nullptr, nullptr, QKb, (int)NT, 2 * D_, D_);

    // V: N=1024, all blocks -> Vt (transposed+sigma), grid 4x64 = 256 blocks
    gemm_sq2<false, false, false, false, false, true><<<dim3(D_ / 256, NT / 128), b512, 0, stream>>>(
        hb, Wtqkv + (size_t)2 * D_ * D_, nullptr, nullptr, nullptr, nullptr, Vtb, (int)NT, D_, D_);

    attn_mfma<<<dim3(T_ / 256, H_, B_), b512, 0, stream>>>(QKb, Vtb, Ab);

    // out = x + attn @ Wo + bo   (grid 4x64 = 256 blocks)
    gemm_sq2<true, false, true, false, false, false><<<dim3(D_ / 256, NT / 128), b512, 0, stream>>>(
        Ab, Wto, bo, x, out, nullptr, nullptr, (int)NT, D_, D_);

    ln_kernel<<<NT, b256, 0, stream>>>(out, g2, be2, hb);

    // ffn1 = relu(h2 @ W1 + b1)  (grid 16x32 = 512 blocks, coalesced bf16 epilogue)
    gemm_sq<true, true, false, true, false><<<dim3(4 * D_ / 256, NT / 256), b512, 0, stream>>>(
        hb, Wt1, b1, nullptr, nullptr, f1, (int)NT, 4 * D_, D_);

    // out = out + ffn1 @ W2 + b2 (grid 4x64 = 256 blocks, K=4096)
    gemm_sq2<true, false, true, false, false, false><<<dim3(D_ / 256, NT / 128), b512, 0, stream>>>(
        f1, Wt2, b2, out, out, nullptr, nullptr, (int)NT, D_, 4 * D_);
}